// Round 12
// baseline (378.597 us; speedup 1.0000x reference)
//
#include <hip/hip_runtime.h>
#include <hip/hip_bf16.h>
#include <stdint.h>

typedef unsigned short u16;
typedef _Float16 f16;
typedef f16 f16x8 __attribute__((ext_vector_type(8)));
typedef __bf16 bf16x8 __attribute__((ext_vector_type(8)));
typedef float f32x4 __attribute__((ext_vector_type(4)));

#define INVT 14.2857142857142857f  // 1/0.07
#define CSH  32.0f                 // extra shift on T-path exponents (softmax-invariant)

__device__ __forceinline__ u16 f2b(float f) {
  __hip_bfloat16 h = __float2bfloat16(f);
  return __builtin_bit_cast(u16, h);
}
__device__ __forceinline__ u16 f2h(float f) {
  f16 h = (f16)f;
  return __builtin_bit_cast(u16, h);
}
__device__ __forceinline__ void g2l16(const void* g, void* l) {
  __builtin_amdgcn_global_load_lds(
      (__attribute__((address_space(1))) void*)(uintptr_t)g,
      (__attribute__((address_space(3))) void*)(uint32_t)(uintptr_t)l, 16, 0, 0);
}

// ---- merged prep: blocks 0..255 do feat->Xh/xnorm; 256..319 do cb->Eh/enorm/Et
// Et stored with per-64-chunk column permutation pi (position 4l+nf = k 16nf+l);
// gemm1 writes Pu in the same pi order, so pi cancels in gemm2's contraction.
__global__ __launch_bounds__(256) void prep_all(const float* __restrict__ feat,
    const float* __restrict__ cb, u16* __restrict__ Xh, float* __restrict__ xnorm,
    u16* __restrict__ Eh, float* __restrict__ enorm, u16* __restrict__ Et) {
  __shared__ __align__(16) char smraw[16640];
  int t = threadIdx.x;
  if (blockIdx.x < 256) {
    float (*sm)[65] = (float(*)[65])smraw;
    int b = blockIdx.x >> 4;
    int hw0 = (blockIdx.x & 15) << 6;
    int hwi = t & 63, ci0 = t >> 6;
    float xs2[2] = {0.f, 0.f};
    int cj = t & 7;
    for (int c0 = 0; c0 < 512; c0 += 64) {
      for (int ci = ci0; ci < 64; ci += 4)
        sm[ci][hwi] = feat[((b * 512 + c0 + ci) << 10) + hw0 + hwi];
      __syncthreads();
      for (int w = 0; w < 2; ++w) {
        int hj = (t >> 3) + (w << 5);
        int n = (b << 10) + hw0 + hj;
        uint32_t hp[4];
        for (int p = 0; p < 4; ++p) {
          float v0 = sm[cj * 8 + p * 2 + 0][hj];
          float v1 = sm[cj * 8 + p * 2 + 1][hj];
          xs2[w] += v0 * v0 + v1 * v1;
          hp[p] = (uint32_t)f2h(v0) | ((uint32_t)f2h(v1) << 16);
        }
        *(uint4*)(Xh + n * 512 + c0 + cj * 8) = make_uint4(hp[0], hp[1], hp[2], hp[3]);
      }
      __syncthreads();
    }
    for (int w = 0; w < 2; ++w) {
      float v = xs2[w];
      v += __shfl_xor(v, 1); v += __shfl_xor(v, 2); v += __shfl_xor(v, 4);
      if (cj == 0) {
        int hj = (t >> 3) + (w << 5);
        xnorm[(b << 10) + hw0 + hj] = v;
      }
    }
  } else {
    u16 (*sm)[72] = (u16(*)[72])smraw;
    int k0 = (blockIdx.x - 256) << 6;
    int kr = t >> 2, q = t & 3;
    float nrm = 0.f;
    for (int c0 = 0; c0 < 512; c0 += 64) {
      const float4* src = (const float4*)(cb + (size_t)(k0 + kr) * 512 + c0 + q * 16);
      float4 v[4];
      uint32_t hw_[8], bw[8];
#pragma unroll
      for (int p = 0; p < 4; ++p) {
        v[p] = src[p];
        nrm += v[p].x * v[p].x + v[p].y * v[p].y + v[p].z * v[p].z + v[p].w * v[p].w;
        hw_[p * 2 + 0] = (uint32_t)f2h(v[p].x) | ((uint32_t)f2h(v[p].y) << 16);
        hw_[p * 2 + 1] = (uint32_t)f2h(v[p].z) | ((uint32_t)f2h(v[p].w) << 16);
        bw[p * 2 + 0] = (uint32_t)f2b(v[p].x) | ((uint32_t)f2b(v[p].y) << 16);
        bw[p * 2 + 1] = (uint32_t)f2b(v[p].z) | ((uint32_t)f2b(v[p].w) << 16);
      }
      uint4* dstE = (uint4*)(Eh + (size_t)(k0 + kr) * 512 + c0 + q * 16);
      dstE[0] = make_uint4(hw_[0], hw_[1], hw_[2], hw_[3]);
      dstE[1] = make_uint4(hw_[4], hw_[5], hw_[6], hw_[7]);
      uint4* dstS = (uint4*)&sm[kr][q * 16];
      dstS[0] = make_uint4(bw[0], bw[1], bw[2], bw[3]);
      dstS[1] = make_uint4(bw[4], bw[5], bw[6], bw[7]);
      __syncthreads();
      int ci = t >> 2;
      uint32_t o[8];
#pragma unroll
      for (int j = 0; j < 8; ++j) {
        int jj0 = 2 * j, jj1 = 2 * j + 1;
        u16 a0 = sm[16 * (jj0 & 3) + q * 4 + (jj0 >> 2)][ci];
        u16 a1 = sm[16 * (jj1 & 3) + q * 4 + (jj1 >> 2)][ci];
        o[j] = (uint32_t)a0 | ((uint32_t)a1 << 16);
      }
      uint4* dstT = (uint4*)(Et + (size_t)(c0 + ci) * 4096 + k0 + q * 16);
      dstT[0] = make_uint4(o[0], o[1], o[2], o[3]);
      dstT[1] = make_uint4(o[4], o[5], o[6], o[7]);
      __syncthreads();
    }
    nrm += __shfl_xor(nrm, 1); nrm += __shfl_xor(nrm, 2);
    if (q == 0) enorm[k0 + kr] = nrm;
  }
}

// ============ GEMM1 (fp16): 256x256 tile, BK=64, 8 waves, 8-phase =============
__device__ __forceinline__ void stageA_g1(const u16* __restrict__ g, u16* l, int h, int t) {
  int r0 = t >> 3, c = ((t & 7) ^ (r0 & 7)) * 8, cw = (t & 7) * 8;
  int ra = h * 64 + r0, rb = 128 + h * 64 + r0;
  g2l16(g + ra * 512 + c, l + ra * 64 + cw);
  g2l16(g + rb * 512 + c, l + rb * 64 + cw);
}
__device__ __forceinline__ void stageB_g1(const u16* __restrict__ g, u16* l, int hb, int t) {
  int r0 = t >> 3, c = ((t & 7) ^ (r0 & 7)) * 8, cw = (t & 7) * 8;
  int ra = (r0 >> 5) * 64 + hb * 32 + (r0 & 31);
  int rb = ((r0 + 64) >> 5) * 64 + hb * 32 + (r0 & 31);
  g2l16(g + ra * 512 + c, l + ra * 64 + cw);
  g2l16(g + rb * 512 + c, l + rb * 64 + cw);
}

template<int Q>
__device__ __forceinline__ void phase_ld(const u16* Ab, const u16* Bb,
    int wm, int wn, int lane16, int kl, f16x8 (&af)[4][2], f16x8 (&bf2)[2][2]) {
  int sw = lane16 & 7;
  if constexpr (Q == 0 || Q == 2) {
#pragma unroll
    for (int m = 0; m < 4; ++m)
#pragma unroll
      for (int s = 0; s < 2; ++s)
        af[m][s] = *(const f16x8*)(Ab + (wm * 128 + ((Q >> 1) * 4 + m) * 16 + lane16) * 64
                                   + (((s * 4 + kl) ^ sw) * 8));
  }
  if constexpr (Q != 2) {
    constexpr int NF0 = (Q == 1) ? 2 : 0;
#pragma unroll
    for (int n = 0; n < 2; ++n)
#pragma unroll
      for (int s = 0; s < 2; ++s)
        bf2[n][s] = *(const f16x8*)(Bb + (wn * 64 + (NF0 + n) * 16 + lane16) * 64
                                    + (((s * 4 + kl) ^ sw) * 8));
  }
}
template<int Q>
__device__ __forceinline__ void phase_mm(f16x8 (&af)[4][2], f16x8 (&bf2)[2][2],
                                         f32x4 (&acc)[8][4]) {
  constexpr int MQ = (Q >> 1) * 4;
  constexpr int NF0 = (Q == 1 || Q == 2) ? 2 : 0;
#pragma unroll
  for (int m = 0; m < 4; ++m)
#pragma unroll
    for (int n = 0; n < 2; ++n)
#pragma unroll
      for (int s = 0; s < 2; ++s)
        acc[MQ + m][NF0 + n] = __builtin_amdgcn_mfma_f32_16x16x32_f16(
            af[m][s], bf2[n][s], acc[MQ + m][NF0 + n], 0, 0, 0);
}

#define FENCE() asm volatile("" ::: "memory")
#define BAR() __builtin_amdgcn_s_barrier()
#define VMW6() asm volatile("s_waitcnt vmcnt(6)" ::: "memory")
#define VMW4() asm volatile("s_waitcnt vmcnt(4)" ::: "memory")
#define VMW0() asm volatile("s_waitcnt vmcnt(0)" ::: "memory")

__global__ __launch_bounds__(512, 2) void gemm1_8ph(const u16* __restrict__ Xh,
    const u16* __restrict__ Eh, const float* __restrict__ xnorm,
    const float* __restrict__ enorm, float* __restrict__ D,
    float* __restrict__ S1p, float* __restrict__ STp, u16* __restrict__ Pu) {
  __shared__ __align__(16) u16 lds[2][2][256 * 64];  // 128 KB
  int bid = blockIdx.x;
  int s = (bid & 7) * 128 + (bid >> 3);   // XCD swizzle, bijective (1024 % 8 == 0)
  int rt = s >> 4, ct = s & 15;
  int n0 = rt << 8, k0 = ct << 8;
  int t = threadIdx.x;
  int l = t & 63, w = t >> 6;
  int wm = w >> 2, wn = w & 3;
  int lane16 = l & 15, kl = l >> 4;

  u16* lA0 = &lds[0][0][0]; u16* lB0 = &lds[0][1][0];
  u16* lA1 = &lds[1][0][0]; u16* lB1 = &lds[1][1][0];

  auto gA = [&](int kt) { return Xh + n0 * 512 + kt * 64; };
  auto gB = [&](int kt) { return Eh + k0 * 512 + kt * 64; };

  f32x4 acc[8][4];
#pragma unroll
  for (int m = 0; m < 8; ++m)
#pragma unroll
    for (int n = 0; n < 4; ++n) acc[m][n] = f32x4{0.f, 0.f, 0.f, 0.f};
  f16x8 af[4][2], bf2[2][2];

  stageA_g1(gA(0), lA0, 0, t);
  stageB_g1(gB(0), lB0, 1, t);
  stageB_g1(gB(0), lB0, 0, t);
  stageA_g1(gA(0), lA0, 1, t);
  stageA_g1(gA(1), lA1, 0, t);
  stageB_g1(gB(1), lB1, 1, t);
  VMW4();
  BAR();

#pragma unroll 1
  for (int i = 0; i < 4; ++i) {
    int ktO = 2 * i + 1;
    int ktE2 = 2 * i + 2, ktO2 = 2 * i + 3;
    bool more = (i < 3);
    phase_ld<0>(lA0, lB0, wm, wn, lane16, kl, af, bf2);
    stageB_g1(gB(ktO), lB1, 0, t);
    FENCE(); BAR();
    __builtin_amdgcn_s_setprio(1); phase_mm<0>(af, bf2, acc); __builtin_amdgcn_s_setprio(0);
    FENCE(); BAR();
    phase_ld<1>(lA0, lB0, wm, wn, lane16, kl, af, bf2);
    stageA_g1(gA(ktO), lA1, 1, t);
    FENCE(); BAR();
    __builtin_amdgcn_s_setprio(1); phase_mm<1>(af, bf2, acc); __builtin_amdgcn_s_setprio(0);
    FENCE(); BAR();
    phase_ld<2>(lA0, lB0, wm, wn, lane16, kl, af, bf2);
    if (more) stageA_g1(gA(ktE2), lA0, 0, t);
    FENCE(); BAR();
    __builtin_amdgcn_s_setprio(1); phase_mm<2>(af, bf2, acc); __builtin_amdgcn_s_setprio(0);
    FENCE(); BAR();
    phase_ld<3>(lA0, lB0, wm, wn, lane16, kl, af, bf2);
    if (more) stageB_g1(gB(ktE2), lB0, 1, t);
    FENCE(); BAR();
    __builtin_amdgcn_s_setprio(1); phase_mm<3>(af, bf2, acc); __builtin_amdgcn_s_setprio(0);
    if (i == 3) { VMW0(); } else { VMW4(); }
    BAR();
    phase_ld<0>(lA1, lB1, wm, wn, lane16, kl, af, bf2);
    if (more) stageB_g1(gB(ktE2), lB0, 0, t);
    FENCE(); BAR();
    __builtin_amdgcn_s_setprio(1); phase_mm<0>(af, bf2, acc); __builtin_amdgcn_s_setprio(0);
    FENCE(); BAR();
    phase_ld<1>(lA1, lB1, wm, wn, lane16, kl, af, bf2);
    if (more) stageA_g1(gA(ktE2), lA0, 1, t);
    FENCE(); BAR();
    __builtin_amdgcn_s_setprio(1); phase_mm<1>(af, bf2, acc); __builtin_amdgcn_s_setprio(0);
    FENCE(); BAR();
    phase_ld<2>(lA1, lB1, wm, wn, lane16, kl, af, bf2);
    if (more) stageA_g1(gA(ktO2), lA1, 0, t);
    FENCE(); BAR();
    __builtin_amdgcn_s_setprio(1); phase_mm<2>(af, bf2, acc); __builtin_amdgcn_s_setprio(0);
    FENCE(); BAR();
    phase_ld<3>(lA1, lB1, wm, wn, lane16, kl, af, bf2);
    if (more) stageB_g1(gB(ktO2), lB1, 1, t);
    FENCE(); BAR();
    __builtin_amdgcn_s_setprio(1); phase_mm<3>(af, bf2, acc); __builtin_amdgcn_s_setprio(0);
    if (more) { VMW4(); }
    BAR();
  }

  // epilogue: D = xnorm - l; Pu = bf16(exp(l)) in pi order; partial exp-sums
  float en[4];
#pragma unroll
  for (int nf = 0; nf < 4; ++nf) en[nf] = enorm[k0 + wn * 64 + nf * 16 + lane16];
  float* ldsS = (float*)&lds[0][0][0];   // [256][4]
  float* ldsT = ldsS + 1024;             // [256][4]
#pragma unroll
  for (int mf = 0; mf < 8; ++mf) {
#pragma unroll
    for (int r = 0; r < 4; ++r) {
      int lrow = wm * 128 + mf * 16 + kl * 4 + r;
      int row = n0 + lrow;
      float xv = xnorm[row];
      float lv[4], ev[4];
#pragma unroll
      for (int nf = 0; nf < 4; ++nf) lv[nf] = 2.0f * acc[mf][nf][r] - en[nf];
      float* Drow = D + (size_t)row * 4096 + k0 + wn * 64 + lane16;
#pragma unroll
      for (int nf = 0; nf < 4; ++nf) Drow[nf * 16] = xv - lv[nf];
#pragma unroll
      for (int nf = 0; nf < 4; ++nf) ev[nf] = __expf(lv[nf]);
      uint2 pp;
      pp.x = (uint32_t)f2b(ev[0]) | ((uint32_t)f2b(ev[1]) << 16);
      pp.y = (uint32_t)f2b(ev[2]) | ((uint32_t)f2b(ev[3]) << 16);
      *(uint2*)(Pu + (size_t)row * 4096 + k0 + wn * 64 + lane16 * 4) = pp;
      float s1 = ev[0] + ev[1] + ev[2] + ev[3];
      float sT = __expf(lv[0] * INVT - CSH) + __expf(lv[1] * INVT - CSH)
               + __expf(lv[2] * INVT - CSH) + __expf(lv[3] * INVT - CSH);
#pragma unroll
      for (int o = 1; o < 16; o <<= 1) { s1 += __shfl_xor(s1, o); sT += __shfl_xor(sT, o); }
      if (lane16 == 0) { ldsS[lrow * 4 + wn] = s1; ldsT[lrow * 4 + wn] = sT; }
    }
  }
  __syncthreads();
  {
    int rr = t & 255;
    if (t < 256) {
      float v = ldsS[rr * 4 + 0] + ldsS[rr * 4 + 1] + ldsS[rr * 4 + 2] + ldsS[rr * 4 + 3];
      S1p[ct * 16384 + n0 + rr] = v;
    } else {
      float v = ldsT[rr * 4 + 0] + ldsT[rr * 4 + 1] + ldsT[rr * 4 + 2] + ldsT[rr * 4 + 3];
      STp[ct * 16384 + n0 + rr] = v;
    }
  }
}

// ------- softmax: combine T-partials + single D pass -> assign (NT stores) ----
__global__ __launch_bounds__(256) void softmax_out(const float* __restrict__ D,
    const float* __restrict__ xnorm, const float* __restrict__ STp,
    float* __restrict__ assign) {
  __shared__ float tt[128][33];
  int n0 = blockIdx.x << 5;
  int b = n0 >> 10, hw0 = n0 & 1023;
  int t = threadIdx.x;
  int i = t >> 3, jc = t & 7;
  int row = n0 + i;
  const float* Dr = D + (size_t)row * 4096;
  float sT = STp[(jc * 2) * 16384 + row] + STp[(jc * 2 + 1) * 16384 + row];
#pragma unroll
  for (int o = 1; o < 8; o <<= 1) sT += __shfl_xor(sT, o);
  float isT = 1.0f / sT;
  float xn = xnorm[row];

  float* assignB = assign + b * 4194304 + hw0;
  for (int kt = 0; kt < 32; ++kt) {
    int kb = kt << 7;
    for (int it = 0; it < 4; ++it) {
      int col4 = (jc + it * 8) * 4;
      float4 dv = *(const float4*)(Dr + kb + col4);
      float e0 = xn - dv.x, e1 = xn - dv.y, e2 = xn - dv.z, e3 = xn - dv.w;
      tt[col4 + 0][i] = __expf(e0 * INVT - CSH) * isT;
      tt[col4 + 1][i] = __expf(e1 * INVT - CSH) * isT;
      tt[col4 + 2][i] = __expf(e2 * INVT - CSH) * isT;
      tt[col4 + 3][i] = __expf(e3 * INVT - CSH) * isT;
    }
    __syncthreads();
    for (int idx = t; idx < 1024; idx += 256) {
      int j = idx >> 3, ic = idx & 7;
      f32x4 o;
      o[0] = tt[j][ic * 4 + 0]; o[1] = tt[j][ic * 4 + 1];
      o[2] = tt[j][ic * 4 + 2]; o[3] = tt[j][ic * 4 + 3];
      __builtin_nontemporal_store(o, (f32x4*)(assignB + (kb + j) * 1024 + ic * 4));
    }
    __syncthreads();
  }
}

// ======== GEMM2 (3-deep, 4-phase/tile): tile 128(c) x 256(n), BK=64 ===========
// q^T = Et . Pu^T scaled by 1/s1[col] (summed from S1p) at epilogue.
// 3 LDS buffers (144 KB): tile kt+2 staged during tile kt -> ~8-phase load
// lookahead covering HBM miss latency; end-of-tile wait is vmcnt(6).
__device__ __forceinline__ void stageA2(const u16* __restrict__ g, u16* l, int h, int t) {
  int ri = t >> 3, ch = t & 7;
  int r = (ri >> 5) * 64 + h * 32 + (ri & 31);
  g2l16(g + (size_t)r * 4096 + ((ch ^ (r & 7)) * 8), l + r * 64 + ch * 8);
}
__device__ __forceinline__ void stageB2(const u16* __restrict__ g, u16* l, int h, int j, int t) {
  int ri = j * 64 + (t >> 3), ch = t & 7;
  int r = (ri >> 5) * 64 + h * 32 + (ri & 31);
  g2l16(g + (size_t)r * 4096 + ((ch ^ (r & 7)) * 8), l + r * 64 + ch * 8);
}

template<int Q>
__device__ __forceinline__ void phase_ld2(const u16* Ab, const u16* Bb,
    int wm, int wn, int lane16, int kl, bf16x8 (&af)[2][2], bf16x8 (&bf)[2][2]) {
  int sw = lane16 & 7;
  if constexpr (Q == 0 || Q == 2) {
#pragma unroll
    for (int m = 0; m < 2; ++m)
#pragma unroll
      for (int s = 0; s < 2; ++s)
        af[m][s] = *(const bf16x8*)(Ab + (wm * 64 + ((Q >> 1) * 2 + m) * 16 + lane16) * 64
                                    + (((s * 4 + kl) ^ sw) * 8));
  }
  if constexpr (Q != 2) {
    constexpr int NF0 = (Q == 1) ? 2 : 0;
#pragma unroll
    for (int n = 0; n < 2; ++n)
#pragma unroll
      for (int s = 0; s < 2; ++s)
        bf[n][s] = *(const bf16x8*)(Bb + (wn * 64 + (NF0 + n) * 16 + lane16) * 64
                                    + (((s * 4 + kl) ^ sw) * 8));
  }
}
template<int Q>
__device__ __forceinline__ void phase_mm2(bf16x8 (&af)[2][2], bf16x8 (&bf)[2][2],
                                          f32x4 (&acc)[4][4]) {
  constexpr int MQ = (Q >> 1) * 2;
  constexpr int NF0 = (Q == 1 || Q == 2) ? 2 : 0;
#pragma unroll
  for (int m = 0; m < 2; ++m)
#pragma unroll
    for (int n = 0; n < 2; ++n)
#pragma unroll
      for (int s = 0; s < 2; ++s)
        acc[MQ + m][NF0 + n] = __builtin_amdgcn_mfma_f32_16x16x32_bf16(
            af[m][s], bf[n][s], acc[MQ + m][NF0 + n], 0, 0, 0);
}

// one K-tile: 4 phases; stage tile kn into (An,Bn) if ST; end wait unless LASTW
#define G2_TILE(Ab, Bb, An, Bn, kn, ST, LASTW) \
  { const u16* gAn = gA + (kn) * 64; const u16* gBn = gB + (kn) * 64; \
    phase_ld2<0>(Ab, Bb, wm, wn, lane16, kl, af, bf); \
    if (ST) { stageA2(gAn, An, 0, t); stageA2(gAn, An, 1, t); } \
    FENCE(); BAR(); \
    __builtin_amdgcn_s_setprio(1); phase_mm2<0>(af, bf, acc); __builtin_amdgcn_s_setprio(0); \
    FENCE(); BAR(); \
    phase_ld2<1>(Ab, Bb, wm, wn, lane16, kl, af, bf); \
    if (ST) { stageB2(gBn, Bn, 0, 0, t); stageB2(gBn, Bn, 0, 1, t); } \
    FENCE(); BAR(); \
    __builtin_amdgcn_s_setprio(1); phase_mm2<1>(af, bf, acc); __builtin_amdgcn_s_setprio(0); \
    FENCE(); BAR(); \
    phase_ld2<2>(Ab, Bb, wm, wn, lane16, kl, af, bf); \
    if (ST) { stageB2(gBn, Bn, 1, 0, t); stageB2(gBn, Bn, 1, 1, t); } \
    FENCE(); BAR(); \
    __builtin_amdgcn_s_setprio(1); phase_mm2<2>(af, bf, acc); __builtin_amdgcn_s_setprio(0); \
    FENCE(); BAR(); \
    phase_ld2<3>(Ab, Bb, wm, wn, lane16, kl, af, bf); \
    FENCE(); BAR(); \
    __builtin_amdgcn_s_setprio(1); phase_mm2<3>(af, bf, acc); __builtin_amdgcn_s_setprio(0); \
    if (!(LASTW)) { if (ST) { VMW6(); } else { VMW0(); } BAR(); } }

__global__ __launch_bounds__(512, 1) void gemm2_3d(const u16* __restrict__ Et,
    const u16* __restrict__ Pu, const float* __restrict__ S1p, float* __restrict__ Q) {
  __shared__ __align__(16) u16 lds[3][384 * 64];  // 3 x (A 16KB + B 32KB) = 144 KB
  int bid = blockIdx.x;
  int s = (bid & 7) * 32 + (bid >> 3);   // 256 blocks, bijective XCD swizzle
  int ct = s >> 2, rt = s & 3;           // 4 c-blocks of an n-panel share an XCD
  int c0 = rt << 7, n0 = ct << 8;
  int t = threadIdx.x;
  int l = t & 63, w = t >> 6;
  int wm = w >> 2, wn = w & 3;
  int lane16 = l & 15, kl = l >> 4;

  u16* A0 = &lds[0][0]; u16* B0 = &lds[0][128 * 64];
  u16* A1 = &lds[1][0]; u16* B1 = &lds[1][128 * 64];
  u16* A2 = &lds[2][0]; u16* B2 = &lds[2][128 * 64];

  const u16* gA = Et + (size_t)c0 * 4096;
  const u16* gB = Pu + (size_t)n0 * 4096;

  f32x4 acc[4][4];
#pragma unroll
  for (int m = 0; m < 4; ++m)
#pragma unroll
    for (int n = 0; n < 4; ++n) acc[m][n] = f32x4{0.f, 0.f, 0.f, 0.f};
  bf16x8 af[2][2], bf[2][2];

  // prologue: tiles 0 (buf0) and 1 (buf1), 12 loads; wait tile0 (6 may remain)
  stageA2(gA + 0 * 64, A0, 0, t); stageA2(gA + 0 * 64, A0, 1, t);
  stageB2(gB + 0 * 64, B0, 0, 0, t); stageB2(gB + 0 * 64, B0, 0, 1, t);
  stageB2(gB + 0 * 64, B0, 1, 0, t); stageB2(gB + 0 * 64, B0, 1, 1, t);
  stageA2(gA + 1 * 64, A1, 0, t); stageA2(gA + 1 * 64, A1, 1, t);
  stageB2(gB + 1 * 64, B1, 0, 0, t); stageB2(gB + 1 * 64, B1, 0, 1, t);
  stageB2(gB + 1 * 64, B1, 1, 0, t); stageB2(gB + 1 * 64, B1, 1, 1, t);
  VMW6();
  BAR();

#pragma unroll 1
  for (int j = 0; j < 20; ++j) {
    int kt = 3 * j;
    G2_TILE(A0, B0, A2, B2, kt + 2, 1, 0);   // tile kt   -> stage kt+2 (buf2)
    G2_TILE(A1, B1, A0, B0, kt + 3, 1, 0);   // tile kt+1 -> stage kt+3 (buf0)
    G2_TILE(A2, B2, A1, B1, kt + 4, 1, 0);   // tile kt+2 -> stage kt+4 (buf1)
  }
  // tiles 60..63
  G2_TILE(A0, B0, A2, B2, 62, 1, 0);         // tile 60 -> stage 62 (buf2)
  G2_TILE(A1, B1, A0, B0, 63, 1, 0);         // tile 61 -> stage 63 (buf0)
  G2_TILE(A2, B2, A1, B1, 0, 0, 0);          // tile 62, no stage, VMW0
  G2_TILE(A0, B0, A1, B1, 0, 0, 1);          // tile 63, last

  // epilogue: invs1 from S1p partials (L2-resident), then scaled NT store
  float iv[4];
#pragma unroll
  for (int nn = 0; nn < 4; ++nn) {
    int col = n0 + wn * 64 + nn * 16 + lane16;
    float ssum = 0.f;
#pragma unroll
    for (int j = 0; j < 16; ++j) ssum += S1p[j * 16384 + col];
    iv[nn] = 1.0f / ssum;
  }
  for (int m = 0; m < 4; ++m) {
    for (int r = 0; r < 4; ++r) {
      int crow = c0 + wm * 64 + m * 16 + kl * 4 + r;
      for (int nn = 0; nn < 4; ++nn) {
        int col = n0 + wn * 64 + nn * 16 + lane16;
        int bb = col >> 10, hw = col & 1023;
        __builtin_nontemporal_store(acc[m][nn][r] * iv[nn],
                                    &Q[bb * 524288 + crow * 1024 + hw]);
      }
    }
  }
}

extern "C" void kernel_launch(void* const* d_in, const int* in_sizes, int n_in,
                              void* d_out, int out_size, void* d_ws, size_t ws_size,
                              hipStream_t stream) {
  const float* feat = (const float*)d_in[0];   // (16, 512, 32, 32)
  const float* cb = (const float*)d_in[1];     // (4096, 512)
  float* out = (float*)d_out;
  float* q_out = out;                          // 8388608
  float* a_out = out + 8388608;                // 67108864
  float* d_dist = out + 75497472;              // 67108864

  char* ws = (char*)d_ws;
  u16* Xh = (u16*)(ws + 0);                    // 16 MB  fp16 X (n,c)
  u16* Eh = (u16*)(ws + 16777216);             // 4 MB   fp16 E (k,c)
  u16* Et = (u16*)(ws + 20971520);             // 4 MB   bf16 E^T (c,k) pi-order
  float* xnorm = (float*)(ws + 25165824);      // 64 KB
  float* enorm = (float*)(ws + 25231360);      // 16 KB
  float* S1p = (float*)(ws + 25247744);        // 1 MB  [16][16384]
  float* STp = (float*)(ws + 26296320);        // 1 MB
  u16* Pu = (u16*)(ws + 27410432);             // 128 MB -> ends ~155 MB

  prep_all<<<320, 256, 0, stream>>>(feat, cb, Xh, xnorm, Eh, enorm, Et);
  gemm1_8ph<<<1024, 512, 0, stream>>>(Xh, Eh, xnorm, enorm, d_dist, S1p, STp, Pu);
  gemm2_3d<<<256, 512, 0, stream>>>(Et, Pu, S1p, q_out);      // before softmax: Pu L3-warm
  softmax_out<<<512, 256, 0, stream>>>(d_dist, xnorm, STp, a_out);
}

// Round 13
// 347.865 us; speedup vs baseline: 1.0883x; 1.0883x over previous
//
#include <hip/hip_runtime.h>
#include <hip/hip_bf16.h>
#include <stdint.h>

typedef unsigned short u16;
typedef _Float16 f16;
typedef f16 f16x8 __attribute__((ext_vector_type(8)));
typedef __bf16 bf16x8 __attribute__((ext_vector_type(8)));
typedef float f32x4 __attribute__((ext_vector_type(4)));

#define INVT 14.2857142857142857f  // 1/0.07
#define CSH  32.0f                 // extra shift on T-path exponents (softmax-invariant)

__device__ __forceinline__ u16 f2b(float f) {
  __hip_bfloat16 h = __float2bfloat16(f);
  return __builtin_bit_cast(u16, h);
}
__device__ __forceinline__ u16 f2h(float f) {
  f16 h = (f16)f;
  return __builtin_bit_cast(u16, h);
}
__device__ __forceinline__ void g2l16(const void* g, void* l) {
  __builtin_amdgcn_global_load_lds(
      (__attribute__((address_space(1))) void*)(uintptr_t)g,
      (__attribute__((address_space(3))) void*)(uint32_t)(uintptr_t)l, 16, 0, 0);
}

// ---- merged prep: blocks 0..255 do feat->Xh/xnorm; 256..319 do cb->Eh/enorm/Et
// Et stored with per-64-chunk column permutation pi (position 4l+nf = k 16nf+l);
// gemm1 writes Pu in the same pi order, so pi cancels in gemm2's contraction.
__global__ __launch_bounds__(256) void prep_all(const float* __restrict__ feat,
    const float* __restrict__ cb, u16* __restrict__ Xh, float* __restrict__ xnorm,
    u16* __restrict__ Eh, float* __restrict__ enorm, u16* __restrict__ Et) {
  __shared__ __align__(16) char smraw[16640];
  int t = threadIdx.x;
  if (blockIdx.x < 256) {
    float (*sm)[65] = (float(*)[65])smraw;
    int b = blockIdx.x >> 4;
    int hw0 = (blockIdx.x & 15) << 6;
    int hwi = t & 63, ci0 = t >> 6;
    float xs2[2] = {0.f, 0.f};
    int cj = t & 7;
    for (int c0 = 0; c0 < 512; c0 += 64) {
      for (int ci = ci0; ci < 64; ci += 4)
        sm[ci][hwi] = feat[((b * 512 + c0 + ci) << 10) + hw0 + hwi];
      __syncthreads();
      for (int w = 0; w < 2; ++w) {
        int hj = (t >> 3) + (w << 5);
        int n = (b << 10) + hw0 + hj;
        uint32_t hp[4];
        for (int p = 0; p < 4; ++p) {
          float v0 = sm[cj * 8 + p * 2 + 0][hj];
          float v1 = sm[cj * 8 + p * 2 + 1][hj];
          xs2[w] += v0 * v0 + v1 * v1;
          hp[p] = (uint32_t)f2h(v0) | ((uint32_t)f2h(v1) << 16);
        }
        *(uint4*)(Xh + n * 512 + c0 + cj * 8) = make_uint4(hp[0], hp[1], hp[2], hp[3]);
      }
      __syncthreads();
    }
    for (int w = 0; w < 2; ++w) {
      float v = xs2[w];
      v += __shfl_xor(v, 1); v += __shfl_xor(v, 2); v += __shfl_xor(v, 4);
      if (cj == 0) {
        int hj = (t >> 3) + (w << 5);
        xnorm[(b << 10) + hw0 + hj] = v;
      }
    }
  } else {
    u16 (*sm)[72] = (u16(*)[72])smraw;
    int k0 = (blockIdx.x - 256) << 6;
    int kr = t >> 2, q = t & 3;
    float nrm = 0.f;
    for (int c0 = 0; c0 < 512; c0 += 64) {
      const float4* src = (const float4*)(cb + (size_t)(k0 + kr) * 512 + c0 + q * 16);
      float4 v[4];
      uint32_t hw_[8], bw[8];
#pragma unroll
      for (int p = 0; p < 4; ++p) {
        v[p] = src[p];
        nrm += v[p].x * v[p].x + v[p].y * v[p].y + v[p].z * v[p].z + v[p].w * v[p].w;
        hw_[p * 2 + 0] = (uint32_t)f2h(v[p].x) | ((uint32_t)f2h(v[p].y) << 16);
        hw_[p * 2 + 1] = (uint32_t)f2h(v[p].z) | ((uint32_t)f2h(v[p].w) << 16);
        bw[p * 2 + 0] = (uint32_t)f2b(v[p].x) | ((uint32_t)f2b(v[p].y) << 16);
        bw[p * 2 + 1] = (uint32_t)f2b(v[p].z) | ((uint32_t)f2b(v[p].w) << 16);
      }
      uint4* dstE = (uint4*)(Eh + (size_t)(k0 + kr) * 512 + c0 + q * 16);
      dstE[0] = make_uint4(hw_[0], hw_[1], hw_[2], hw_[3]);
      dstE[1] = make_uint4(hw_[4], hw_[5], hw_[6], hw_[7]);
      uint4* dstS = (uint4*)&sm[kr][q * 16];
      dstS[0] = make_uint4(bw[0], bw[1], bw[2], bw[3]);
      dstS[1] = make_uint4(bw[4], bw[5], bw[6], bw[7]);
      __syncthreads();
      int ci = t >> 2;
      uint32_t o[8];
#pragma unroll
      for (int j = 0; j < 8; ++j) {
        int jj0 = 2 * j, jj1 = 2 * j + 1;
        u16 a0 = sm[16 * (jj0 & 3) + q * 4 + (jj0 >> 2)][ci];
        u16 a1 = sm[16 * (jj1 & 3) + q * 4 + (jj1 >> 2)][ci];
        o[j] = (uint32_t)a0 | ((uint32_t)a1 << 16);
      }
      uint4* dstT = (uint4*)(Et + (size_t)(c0 + ci) * 4096 + k0 + q * 16);
      dstT[0] = make_uint4(o[0], o[1], o[2], o[3]);
      dstT[1] = make_uint4(o[4], o[5], o[6], o[7]);
      __syncthreads();
    }
    nrm += __shfl_xor(nrm, 1); nrm += __shfl_xor(nrm, 2);
    if (q == 0) enorm[k0 + kr] = nrm;
  }
}

// ============ GEMM1 (fp16): 256x256 tile, BK=64, 8 waves, 8-phase =============
__device__ __forceinline__ void stageA_g1(const u16* __restrict__ g, u16* l, int h, int t) {
  int r0 = t >> 3, c = ((t & 7) ^ (r0 & 7)) * 8, cw = (t & 7) * 8;
  int ra = h * 64 + r0, rb = 128 + h * 64 + r0;
  g2l16(g + ra * 512 + c, l + ra * 64 + cw);
  g2l16(g + rb * 512 + c, l + rb * 64 + cw);
}
__device__ __forceinline__ void stageB_g1(const u16* __restrict__ g, u16* l, int hb, int t) {
  int r0 = t >> 3, c = ((t & 7) ^ (r0 & 7)) * 8, cw = (t & 7) * 8;
  int ra = (r0 >> 5) * 64 + hb * 32 + (r0 & 31);
  int rb = ((r0 + 64) >> 5) * 64 + hb * 32 + (r0 & 31);
  g2l16(g + ra * 512 + c, l + ra * 64 + cw);
  g2l16(g + rb * 512 + c, l + rb * 64 + cw);
}

template<int Q>
__device__ __forceinline__ void phase_ld(const u16* Ab, const u16* Bb,
    int wm, int wn, int lane16, int kl, f16x8 (&af)[4][2], f16x8 (&bf2)[2][2]) {
  int sw = lane16 & 7;
  if constexpr (Q == 0 || Q == 2) {
#pragma unroll
    for (int m = 0; m < 4; ++m)
#pragma unroll
      for (int s = 0; s < 2; ++s)
        af[m][s] = *(const f16x8*)(Ab + (wm * 128 + ((Q >> 1) * 4 + m) * 16 + lane16) * 64
                                   + (((s * 4 + kl) ^ sw) * 8));
  }
  if constexpr (Q != 2) {
    constexpr int NF0 = (Q == 1) ? 2 : 0;
#pragma unroll
    for (int n = 0; n < 2; ++n)
#pragma unroll
      for (int s = 0; s < 2; ++s)
        bf2[n][s] = *(const f16x8*)(Bb + (wn * 64 + (NF0 + n) * 16 + lane16) * 64
                                    + (((s * 4 + kl) ^ sw) * 8));
  }
}
template<int Q>
__device__ __forceinline__ void phase_mm(f16x8 (&af)[4][2], f16x8 (&bf2)[2][2],
                                         f32x4 (&acc)[8][4]) {
  constexpr int MQ = (Q >> 1) * 4;
  constexpr int NF0 = (Q == 1 || Q == 2) ? 2 : 0;
#pragma unroll
  for (int m = 0; m < 4; ++m)
#pragma unroll
    for (int n = 0; n < 2; ++n)
#pragma unroll
      for (int s = 0; s < 2; ++s)
        acc[MQ + m][NF0 + n] = __builtin_amdgcn_mfma_f32_16x16x32_f16(
            af[m][s], bf2[n][s], acc[MQ + m][NF0 + n], 0, 0, 0);
}

#define FENCE() asm volatile("" ::: "memory")
#define BAR() __builtin_amdgcn_s_barrier()
#define VMW6() asm volatile("s_waitcnt vmcnt(6)" ::: "memory")
#define VMW4() asm volatile("s_waitcnt vmcnt(4)" ::: "memory")
#define VMW0() asm volatile("s_waitcnt vmcnt(0)" ::: "memory")

__global__ __launch_bounds__(512, 2) void gemm1_8ph(const u16* __restrict__ Xh,
    const u16* __restrict__ Eh, const float* __restrict__ xnorm,
    const float* __restrict__ enorm, float* __restrict__ D,
    float* __restrict__ S1p, float* __restrict__ STp, u16* __restrict__ Pu) {
  __shared__ __align__(16) u16 lds[2][2][256 * 64];  // 128 KB
  int bid = blockIdx.x;
  int s = (bid & 7) * 128 + (bid >> 3);   // XCD swizzle, bijective (1024 % 8 == 0)
  int rt = s >> 4, ct = s & 15;
  int n0 = rt << 8, k0 = ct << 8;
  int t = threadIdx.x;
  int l = t & 63, w = t >> 6;
  int wm = w >> 2, wn = w & 3;
  int lane16 = l & 15, kl = l >> 4;

  u16* lA0 = &lds[0][0][0]; u16* lB0 = &lds[0][1][0];
  u16* lA1 = &lds[1][0][0]; u16* lB1 = &lds[1][1][0];

  auto gA = [&](int kt) { return Xh + n0 * 512 + kt * 64; };
  auto gB = [&](int kt) { return Eh + k0 * 512 + kt * 64; };

  f32x4 acc[8][4];
#pragma unroll
  for (int m = 0; m < 8; ++m)
#pragma unroll
    for (int n = 0; n < 4; ++n) acc[m][n] = f32x4{0.f, 0.f, 0.f, 0.f};
  f16x8 af[4][2], bf2[2][2];

  stageA_g1(gA(0), lA0, 0, t);
  stageB_g1(gB(0), lB0, 1, t);
  stageB_g1(gB(0), lB0, 0, t);
  stageA_g1(gA(0), lA0, 1, t);
  stageA_g1(gA(1), lA1, 0, t);
  stageB_g1(gB(1), lB1, 1, t);
  VMW4();
  BAR();

#pragma unroll 1
  for (int i = 0; i < 4; ++i) {
    int ktO = 2 * i + 1;
    int ktE2 = 2 * i + 2, ktO2 = 2 * i + 3;
    bool more = (i < 3);
    phase_ld<0>(lA0, lB0, wm, wn, lane16, kl, af, bf2);
    stageB_g1(gB(ktO), lB1, 0, t);
    FENCE(); BAR();
    __builtin_amdgcn_s_setprio(1); phase_mm<0>(af, bf2, acc); __builtin_amdgcn_s_setprio(0);
    FENCE(); BAR();
    phase_ld<1>(lA0, lB0, wm, wn, lane16, kl, af, bf2);
    stageA_g1(gA(ktO), lA1, 1, t);
    FENCE(); BAR();
    __builtin_amdgcn_s_setprio(1); phase_mm<1>(af, bf2, acc); __builtin_amdgcn_s_setprio(0);
    FENCE(); BAR();
    phase_ld<2>(lA0, lB0, wm, wn, lane16, kl, af, bf2);
    if (more) stageA_g1(gA(ktE2), lA0, 0, t);
    FENCE(); BAR();
    __builtin_amdgcn_s_setprio(1); phase_mm<2>(af, bf2, acc); __builtin_amdgcn_s_setprio(0);
    FENCE(); BAR();
    phase_ld<3>(lA0, lB0, wm, wn, lane16, kl, af, bf2);
    if (more) stageB_g1(gB(ktE2), lB0, 1, t);
    FENCE(); BAR();
    __builtin_amdgcn_s_setprio(1); phase_mm<3>(af, bf2, acc); __builtin_amdgcn_s_setprio(0);
    if (i == 3) { VMW0(); } else { VMW4(); }
    BAR();
    phase_ld<0>(lA1, lB1, wm, wn, lane16, kl, af, bf2);
    if (more) stageB_g1(gB(ktE2), lB0, 0, t);
    FENCE(); BAR();
    __builtin_amdgcn_s_setprio(1); phase_mm<0>(af, bf2, acc); __builtin_amdgcn_s_setprio(0);
    FENCE(); BAR();
    phase_ld<1>(lA1, lB1, wm, wn, lane16, kl, af, bf2);
    if (more) stageA_g1(gA(ktE2), lA0, 1, t);
    FENCE(); BAR();
    __builtin_amdgcn_s_setprio(1); phase_mm<1>(af, bf2, acc); __builtin_amdgcn_s_setprio(0);
    FENCE(); BAR();
    phase_ld<2>(lA1, lB1, wm, wn, lane16, kl, af, bf2);
    if (more) stageA_g1(gA(ktO2), lA1, 0, t);
    FENCE(); BAR();
    __builtin_amdgcn_s_setprio(1); phase_mm<2>(af, bf2, acc); __builtin_amdgcn_s_setprio(0);
    FENCE(); BAR();
    phase_ld<3>(lA1, lB1, wm, wn, lane16, kl, af, bf2);
    if (more) stageB_g1(gB(ktO2), lB1, 1, t);
    FENCE(); BAR();
    __builtin_amdgcn_s_setprio(1); phase_mm<3>(af, bf2, acc); __builtin_amdgcn_s_setprio(0);
    if (more) { VMW4(); }
    BAR();
  }

  // epilogue: D = xnorm - l; Pu = bf16(exp(l)) in pi order; partial exp-sums
  float en[4];
#pragma unroll
  for (int nf = 0; nf < 4; ++nf) en[nf] = enorm[k0 + wn * 64 + nf * 16 + lane16];
  float* ldsS = (float*)&lds[0][0][0];   // [256][4]
  float* ldsT = ldsS + 1024;             // [256][4]
#pragma unroll
  for (int mf = 0; mf < 8; ++mf) {
#pragma unroll
    for (int r = 0; r < 4; ++r) {
      int lrow = wm * 128 + mf * 16 + kl * 4 + r;
      int row = n0 + lrow;
      float xv = xnorm[row];
      float lv[4], ev[4];
#pragma unroll
      for (int nf = 0; nf < 4; ++nf) lv[nf] = 2.0f * acc[mf][nf][r] - en[nf];
      float* Drow = D + (size_t)row * 4096 + k0 + wn * 64 + lane16;
#pragma unroll
      for (int nf = 0; nf < 4; ++nf) Drow[nf * 16] = xv - lv[nf];
#pragma unroll
      for (int nf = 0; nf < 4; ++nf) ev[nf] = __expf(lv[nf]);
      uint2 pp;
      pp.x = (uint32_t)f2b(ev[0]) | ((uint32_t)f2b(ev[1]) << 16);
      pp.y = (uint32_t)f2b(ev[2]) | ((uint32_t)f2b(ev[3]) << 16);
      *(uint2*)(Pu + (size_t)row * 4096 + k0 + wn * 64 + lane16 * 4) = pp;
      float s1 = ev[0] + ev[1] + ev[2] + ev[3];
      float sT = __expf(lv[0] * INVT - CSH) + __expf(lv[1] * INVT - CSH)
               + __expf(lv[2] * INVT - CSH) + __expf(lv[3] * INVT - CSH);
#pragma unroll
      for (int o = 1; o < 16; o <<= 1) { s1 += __shfl_xor(s1, o); sT += __shfl_xor(sT, o); }
      if (lane16 == 0) { ldsS[lrow * 4 + wn] = s1; ldsT[lrow * 4 + wn] = sT; }
    }
  }
  __syncthreads();
  {
    int rr = t & 255;
    if (t < 256) {
      float v = ldsS[rr * 4 + 0] + ldsS[rr * 4 + 1] + ldsS[rr * 4 + 2] + ldsS[rr * 4 + 3];
      S1p[ct * 16384 + n0 + rr] = v;
    } else {
      float v = ldsT[rr * 4 + 0] + ldsT[rr * 4 + 1] + ldsT[rr * 4 + 2] + ldsT[rr * 4 + 3];
      STp[ct * 16384 + n0 + rr] = v;
    }
  }
}

// ------- softmax: combine T-partials + single D pass -> assign (NT stores) ----
__global__ __launch_bounds__(256) void softmax_out(const float* __restrict__ D,
    const float* __restrict__ xnorm, const float* __restrict__ STp,
    float* __restrict__ assign) {
  __shared__ float tt[128][33];
  int n0 = blockIdx.x << 5;
  int b = n0 >> 10, hw0 = n0 & 1023;
  int t = threadIdx.x;
  int i = t >> 3, jc = t & 7;
  int row = n0 + i;
  const float* Dr = D + (size_t)row * 4096;
  float sT = STp[(jc * 2) * 16384 + row] + STp[(jc * 2 + 1) * 16384 + row];
#pragma unroll
  for (int o = 1; o < 8; o <<= 1) sT += __shfl_xor(sT, o);
  float isT = 1.0f / sT;
  float xn = xnorm[row];

  float* assignB = assign + b * 4194304 + hw0;
  for (int kt = 0; kt < 32; ++kt) {
    int kb = kt << 7;
    for (int it = 0; it < 4; ++it) {
      int col4 = (jc + it * 8) * 4;
      float4 dv = *(const float4*)(Dr + kb + col4);
      float e0 = xn - dv.x, e1 = xn - dv.y, e2 = xn - dv.z, e3 = xn - dv.w;
      tt[col4 + 0][i] = __expf(e0 * INVT - CSH) * isT;
      tt[col4 + 1][i] = __expf(e1 * INVT - CSH) * isT;
      tt[col4 + 2][i] = __expf(e2 * INVT - CSH) * isT;
      tt[col4 + 3][i] = __expf(e3 * INVT - CSH) * isT;
    }
    __syncthreads();
    for (int idx = t; idx < 1024; idx += 256) {
      int j = idx >> 3, ic = idx & 7;
      f32x4 o;
      o[0] = tt[j][ic * 4 + 0]; o[1] = tt[j][ic * 4 + 1];
      o[2] = tt[j][ic * 4 + 2]; o[3] = tt[j][ic * 4 + 3];
      __builtin_nontemporal_store(o, (f32x4*)(assignB + (kb + j) * 1024 + ic * 4));
    }
    __syncthreads();
  }
}

// ======== GEMM2 (3-deep, 4-phase/tile): tile 128(c) x 256(n), BK=64 ===========
// q^T = Et . Pu^T scaled by 1/s1[col] (summed from S1p) at epilogue.
// 3 LDS buffers (144 KB): tile kt+2 staged during tile kt -> ~8-phase load
// lookahead covering HBM miss latency; end-of-tile wait is vmcnt(6).
__device__ __forceinline__ void stageA2(const u16* __restrict__ g, u16* l, int h, int t) {
  int ri = t >> 3, ch = t & 7;
  int r = (ri >> 5) * 64 + h * 32 + (ri & 31);
  g2l16(g + (size_t)r * 4096 + ((ch ^ (r & 7)) * 8), l + r * 64 + ch * 8);
}
__device__ __forceinline__ void stageB2(const u16* __restrict__ g, u16* l, int h, int j, int t) {
  int ri = j * 64 + (t >> 3), ch = t & 7;
  int r = (ri >> 5) * 64 + h * 32 + (ri & 31);
  g2l16(g + (size_t)r * 4096 + ((ch ^ (r & 7)) * 8), l + r * 64 + ch * 8);
}

template<int Q>
__device__ __forceinline__ void phase_ld2(const u16* Ab, const u16* Bb,
    int wm, int wn, int lane16, int kl, bf16x8 (&af)[2][2], bf16x8 (&bf)[2][2]) {
  int sw = lane16 & 7;
  if constexpr (Q == 0 || Q == 2) {
#pragma unroll
    for (int m = 0; m < 2; ++m)
#pragma unroll
      for (int s = 0; s < 2; ++s)
        af[m][s] = *(const bf16x8*)(Ab + (wm * 64 + ((Q >> 1) * 2 + m) * 16 + lane16) * 64
                                    + (((s * 4 + kl) ^ sw) * 8));
  }
  if constexpr (Q != 2) {
    constexpr int NF0 = (Q == 1) ? 2 : 0;
#pragma unroll
    for (int n = 0; n < 2; ++n)
#pragma unroll
      for (int s = 0; s < 2; ++s)
        bf[n][s] = *(const bf16x8*)(Bb + (wn * 64 + (NF0 + n) * 16 + lane16) * 64
                                    + (((s * 4 + kl) ^ sw) * 8));
  }
}
template<int Q>
__device__ __forceinline__ void phase_mm2(bf16x8 (&af)[2][2], bf16x8 (&bf)[2][2],
                                          f32x4 (&acc)[4][4]) {
  constexpr int MQ = (Q >> 1) * 2;
  constexpr int NF0 = (Q == 1 || Q == 2) ? 2 : 0;
#pragma unroll
  for (int m = 0; m < 2; ++m)
#pragma unroll
    for (int n = 0; n < 2; ++n)
#pragma unroll
      for (int s = 0; s < 2; ++s)
        acc[MQ + m][NF0 + n] = __builtin_amdgcn_mfma_f32_16x16x32_bf16(
            af[m][s], bf[n][s], acc[MQ + m][NF0 + n], 0, 0, 0);
}

// one K-tile: 4 phases; stage tile kn into (An,Bn) if ST; end wait unless LASTW
#define G2_TILE(Ab, Bb, An, Bn, kn, ST, LASTW) \
  { const u16* gAn = gA + (kn) * 64; const u16* gBn = gB + (kn) * 64; \
    phase_ld2<0>(Ab, Bb, wm, wn, lane16, kl, af, bf); \
    if (ST) { stageA2(gAn, An, 0, t); stageA2(gAn, An, 1, t); } \
    FENCE(); BAR(); \
    __builtin_amdgcn_s_setprio(1); phase_mm2<0>(af, bf, acc); __builtin_amdgcn_s_setprio(0); \
    FENCE(); BAR(); \
    phase_ld2<1>(Ab, Bb, wm, wn, lane16, kl, af, bf); \
    if (ST) { stageB2(gBn, Bn, 0, 0, t); stageB2(gBn, Bn, 0, 1, t); } \
    FENCE(); BAR(); \
    __builtin_amdgcn_s_setprio(1); phase_mm2<1>(af, bf, acc); __builtin_amdgcn_s_setprio(0); \
    FENCE(); BAR(); \
    phase_ld2<2>(Ab, Bb, wm, wn, lane16, kl, af, bf); \
    if (ST) { stageB2(gBn, Bn, 1, 0, t); stageB2(gBn, Bn, 1, 1, t); } \
    FENCE(); BAR(); \
    __builtin_amdgcn_s_setprio(1); phase_mm2<2>(af, bf, acc); __builtin_amdgcn_s_setprio(0); \
    FENCE(); BAR(); \
    phase_ld2<3>(Ab, Bb, wm, wn, lane16, kl, af, bf); \
    FENCE(); BAR(); \
    __builtin_amdgcn_s_setprio(1); phase_mm2<3>(af, bf, acc); __builtin_amdgcn_s_setprio(0); \
    if (!(LASTW)) { if (ST) { VMW6(); } else { VMW0(); } BAR(); } }

__global__ __launch_bounds__(512, 1) void gemm2_3d(const u16* __restrict__ Et,
    const u16* __restrict__ Pu, const float* __restrict__ S1p, float* __restrict__ Q) {
  __shared__ __align__(16) u16 lds[3][384 * 64];  // 3 x (A 16KB + B 32KB) = 144 KB
  int bid = blockIdx.x;
  int s = (bid & 7) * 32 + (bid >> 3);   // 256 blocks, bijective XCD swizzle
  int ct = s >> 2, rt = s & 3;           // 4 c-blocks of an n-panel share an XCD
  int c0 = rt << 7, n0 = ct << 8;
  int t = threadIdx.x;
  int l = t & 63, w = t >> 6;
  int wm = w >> 2, wn = w & 3;
  int lane16 = l & 15, kl = l >> 4;

  u16* A0 = &lds[0][0]; u16* B0 = &lds[0][128 * 64];
  u16* A1 = &lds[1][0]; u16* B1 = &lds[1][128 * 64];
  u16* A2 = &lds[2][0]; u16* B2 = &lds[2][128 * 64];

  const u16* gA = Et + (size_t)c0 * 4096;
  const u16* gB = Pu + (size_t)n0 * 4096;

  f32x4 acc[4][4];
#pragma unroll
  for (int m = 0; m < 4; ++m)
#pragma unroll
    for (int n = 0; n < 4; ++n) acc[m][n] = f32x4{0.f, 0.f, 0.f, 0.f};
  bf16x8 af[2][2], bf[2][2];

  // prologue: tiles 0 (buf0) and 1 (buf1), 12 loads; wait tile0 (6 may remain)
  stageA2(gA + 0 * 64, A0, 0, t); stageA2(gA + 0 * 64, A0, 1, t);
  stageB2(gB + 0 * 64, B0, 0, 0, t); stageB2(gB + 0 * 64, B0, 0, 1, t);
  stageB2(gB + 0 * 64, B0, 1, 0, t); stageB2(gB + 0 * 64, B0, 1, 1, t);
  stageA2(gA + 1 * 64, A1, 0, t); stageA2(gA + 1 * 64, A1, 1, t);
  stageB2(gB + 1 * 64, B1, 0, 0, t); stageB2(gB + 1 * 64, B1, 0, 1, t);
  stageB2(gB + 1 * 64, B1, 1, 0, t); stageB2(gB + 1 * 64, B1, 1, 1, t);
  VMW6();
  BAR();

#pragma unroll 1
  for (int j = 0; j < 20; ++j) {
    int kt = 3 * j;
    G2_TILE(A0, B0, A2, B2, kt + 2, 1, 0);   // tile kt   -> stage kt+2 (buf2)
    G2_TILE(A1, B1, A0, B0, kt + 3, 1, 0);   // tile kt+1 -> stage kt+3 (buf0)
    G2_TILE(A2, B2, A1, B1, kt + 4, 1, 0);   // tile kt+2 -> stage kt+4 (buf1)
  }
  // tiles 60..63
  G2_TILE(A0, B0, A2, B2, 62, 1, 0);         // tile 60 -> stage 62 (buf2)
  G2_TILE(A1, B1, A0, B0, 63, 1, 0);         // tile 61 -> stage 63 (buf0)
  G2_TILE(A2, B2, A1, B1, 0, 0, 0);          // tile 62, no stage, VMW0
  G2_TILE(A0, B0, A1, B1, 0, 0, 1);          // tile 63, last

  // epilogue: invs1 from S1p partials (L2-resident), then scaled NT store
  float iv[4];
#pragma unroll
  for (int nn = 0; nn < 4; ++nn) {
    int col = n0 + wn * 64 + nn * 16 + lane16;
    float ssum = 0.f;
#pragma unroll
    for (int j = 0; j < 16; ++j) ssum += S1p[j * 16384 + col];
    iv[nn] = 1.0f / ssum;
  }
  for (int m = 0; m < 4; ++m) {
    for (int r = 0; r < 4; ++r) {
      int crow = c0 + wm * 64 + m * 16 + kl * 4 + r;
      for (int nn = 0; nn < 4; ++nn) {
        int col = n0 + wn * 64 + nn * 16 + lane16;
        int bb = col >> 10, hw = col & 1023;
        __builtin_nontemporal_store(acc[m][nn][r] * iv[nn],
                                    &Q[bb * 524288 + crow * 1024 + hw]);
      }
    }
  }
}

extern "C" void kernel_launch(void* const* d_in, const int* in_sizes, int n_in,
                              void* d_out, int out_size, void* d_ws, size_t ws_size,
                              hipStream_t stream) {
  const float* feat = (const float*)d_in[0];   // (16, 512, 32, 32)
  const float* cb = (const float*)d_in[1];     // (4096, 512)
  float* out = (float*)d_out;
  float* q_out = out;                          // 8388608
  float* a_out = out + 8388608;                // 67108864
  float* d_dist = out + 75497472;              // 67108864

  char* ws = (char*)d_ws;
  u16* Xh = (u16*)(ws + 0);                    // 16 MB  fp16 X (n,c)
  u16* Eh = (u16*)(ws + 16777216);             // 4 MB   fp16 E (k,c)
  u16* Et = (u16*)(ws + 20971520);             // 4 MB   bf16 E^T (c,k) pi-order
  float* xnorm = (float*)(ws + 25165824);      // 64 KB
  float* enorm = (float*)(ws + 25231360);      // 16 KB
  float* S1p = (float*)(ws + 25247744);        // 1 MB  [16][16384]
  float* STp = (float*)(ws + 26296320);        // 1 MB
  u16* Pu = (u16*)(ws + 27410432);             // 128 MB -> ends ~155 MB

  prep_all<<<320, 256, 0, stream>>>(feat, cb, Xh, xnorm, Eh, enorm, Et);
  gemm1_8ph<<<1024, 512, 0, stream>>>(Xh, Eh, xnorm, enorm, d_dist, S1p, STp, Pu);
  softmax_out<<<512, 256, 0, stream>>>(d_dist, xnorm, STp, a_out);   // D L3-warm
  gemm2_3d<<<256, 512, 0, stream>>>(Et, Pu, S1p, q_out);
}

// Round 14
// 336.070 us; speedup vs baseline: 1.1265x; 1.0351x over previous
//
#include <hip/hip_runtime.h>
#include <hip/hip_bf16.h>
#include <stdint.h>

typedef unsigned short u16;
typedef _Float16 f16;
typedef f16 f16x8 __attribute__((ext_vector_type(8)));
typedef __bf16 bf16x8 __attribute__((ext_vector_type(8)));
typedef float f32x4 __attribute__((ext_vector_type(4)));
typedef uint32_t u32x2 __attribute__((ext_vector_type(2)));

#define INVT 14.2857142857142857f  // 1/0.07
#define CSH  32.0f                 // extra shift on T-path exponents (softmax-invariant)

__device__ __forceinline__ u16 f2b(float f) {
  __hip_bfloat16 h = __float2bfloat16(f);
  return __builtin_bit_cast(u16, h);
}
__device__ __forceinline__ u16 f2h(float f) {
  f16 h = (f16)f;
  return __builtin_bit_cast(u16, h);
}
__device__ __forceinline__ void g2l16(const void* g, void* l) {
  __builtin_amdgcn_global_load_lds(
      (__attribute__((address_space(1))) void*)(uintptr_t)g,
      (__attribute__((address_space(3))) void*)(uint32_t)(uintptr_t)l, 16, 0, 0);
}

// ---- merged prep: blocks 0..255 do feat->Xh/xnorm; 256..319 do cb->Eh/enorm/Et
// Et stored with per-64-chunk column permutation pi (position 4l+nf = k 16nf+l);
// gemm1 writes Pu in the same pi order, so pi cancels in gemm2's contraction.
__global__ __launch_bounds__(256) void prep_all(const float* __restrict__ feat,
    const float* __restrict__ cb, u16* __restrict__ Xh, float* __restrict__ xnorm,
    u16* __restrict__ Eh, float* __restrict__ enorm, u16* __restrict__ Et) {
  __shared__ __align__(16) char smraw[16640];
  int t = threadIdx.x;
  if (blockIdx.x < 256) {
    float (*sm)[65] = (float(*)[65])smraw;
    int b = blockIdx.x >> 4;
    int hw0 = (blockIdx.x & 15) << 6;
    int hwi = t & 63, ci0 = t >> 6;
    float xs2[2] = {0.f, 0.f};
    int cj = t & 7;
    for (int c0 = 0; c0 < 512; c0 += 64) {
      for (int ci = ci0; ci < 64; ci += 4)
        sm[ci][hwi] = feat[((b * 512 + c0 + ci) << 10) + hw0 + hwi];
      __syncthreads();
      for (int w = 0; w < 2; ++w) {
        int hj = (t >> 3) + (w << 5);
        int n = (b << 10) + hw0 + hj;
        uint32_t hp[4];
        for (int p = 0; p < 4; ++p) {
          float v0 = sm[cj * 8 + p * 2 + 0][hj];
          float v1 = sm[cj * 8 + p * 2 + 1][hj];
          xs2[w] += v0 * v0 + v1 * v1;
          hp[p] = (uint32_t)f2h(v0) | ((uint32_t)f2h(v1) << 16);
        }
        *(uint4*)(Xh + n * 512 + c0 + cj * 8) = make_uint4(hp[0], hp[1], hp[2], hp[3]);
      }
      __syncthreads();
    }
    for (int w = 0; w < 2; ++w) {
      float v = xs2[w];
      v += __shfl_xor(v, 1); v += __shfl_xor(v, 2); v += __shfl_xor(v, 4);
      if (cj == 0) {
        int hj = (t >> 3) + (w << 5);
        xnorm[(b << 10) + hw0 + hj] = v;
      }
    }
  } else {
    u16 (*sm)[72] = (u16(*)[72])smraw;
    int k0 = (blockIdx.x - 256) << 6;
    int kr = t >> 2, q = t & 3;
    float nrm = 0.f;
    for (int c0 = 0; c0 < 512; c0 += 64) {
      const float4* src = (const float4*)(cb + (size_t)(k0 + kr) * 512 + c0 + q * 16);
      float4 v[4];
      uint32_t hw_[8], bw[8];
#pragma unroll
      for (int p = 0; p < 4; ++p) {
        v[p] = src[p];
        nrm += v[p].x * v[p].x + v[p].y * v[p].y + v[p].z * v[p].z + v[p].w * v[p].w;
        hw_[p * 2 + 0] = (uint32_t)f2h(v[p].x) | ((uint32_t)f2h(v[p].y) << 16);
        hw_[p * 2 + 1] = (uint32_t)f2h(v[p].z) | ((uint32_t)f2h(v[p].w) << 16);
        bw[p * 2 + 0] = (uint32_t)f2b(v[p].x) | ((uint32_t)f2b(v[p].y) << 16);
        bw[p * 2 + 1] = (uint32_t)f2b(v[p].z) | ((uint32_t)f2b(v[p].w) << 16);
      }
      uint4* dstE = (uint4*)(Eh + (size_t)(k0 + kr) * 512 + c0 + q * 16);
      dstE[0] = make_uint4(hw_[0], hw_[1], hw_[2], hw_[3]);
      dstE[1] = make_uint4(hw_[4], hw_[5], hw_[6], hw_[7]);
      uint4* dstS = (uint4*)&sm[kr][q * 16];
      dstS[0] = make_uint4(bw[0], bw[1], bw[2], bw[3]);
      dstS[1] = make_uint4(bw[4], bw[5], bw[6], bw[7]);
      __syncthreads();
      int ci = t >> 2;
      uint32_t o[8];
#pragma unroll
      for (int j = 0; j < 8; ++j) {
        int jj0 = 2 * j, jj1 = 2 * j + 1;
        u16 a0 = sm[16 * (jj0 & 3) + q * 4 + (jj0 >> 2)][ci];
        u16 a1 = sm[16 * (jj1 & 3) + q * 4 + (jj1 >> 2)][ci];
        o[j] = (uint32_t)a0 | ((uint32_t)a1 << 16);
      }
      uint4* dstT = (uint4*)(Et + (size_t)(c0 + ci) * 4096 + k0 + q * 16);
      dstT[0] = make_uint4(o[0], o[1], o[2], o[3]);
      dstT[1] = make_uint4(o[4], o[5], o[6], o[7]);
      __syncthreads();
    }
    nrm += __shfl_xor(nrm, 1); nrm += __shfl_xor(nrm, 2);
    if (q == 0) enorm[k0 + kr] = nrm;
  }
}

// ============ GEMM1 (fp16): 256x256 tile, BK=64, 8 waves, 8-phase =============
__device__ __forceinline__ void stageA_g1(const u16* __restrict__ g, u16* l, int h, int t) {
  int r0 = t >> 3, c = ((t & 7) ^ (r0 & 7)) * 8, cw = (t & 7) * 8;
  int ra = h * 64 + r0, rb = 128 + h * 64 + r0;
  g2l16(g + ra * 512 + c, l + ra * 64 + cw);
  g2l16(g + rb * 512 + c, l + rb * 64 + cw);
}
__device__ __forceinline__ void stageB_g1(const u16* __restrict__ g, u16* l, int hb, int t) {
  int r0 = t >> 3, c = ((t & 7) ^ (r0 & 7)) * 8, cw = (t & 7) * 8;
  int ra = (r0 >> 5) * 64 + hb * 32 + (r0 & 31);
  int rb = ((r0 + 64) >> 5) * 64 + hb * 32 + (r0 & 31);
  g2l16(g + ra * 512 + c, l + ra * 64 + cw);
  g2l16(g + rb * 512 + c, l + rb * 64 + cw);
}

template<int Q>
__device__ __forceinline__ void phase_ld(const u16* Ab, const u16* Bb,
    int wm, int wn, int lane16, int kl, f16x8 (&af)[4][2], f16x8 (&bf2)[2][2]) {
  int sw = lane16 & 7;
  if constexpr (Q == 0 || Q == 2) {
#pragma unroll
    for (int m = 0; m < 4; ++m)
#pragma unroll
      for (int s = 0; s < 2; ++s)
        af[m][s] = *(const f16x8*)(Ab + (wm * 128 + ((Q >> 1) * 4 + m) * 16 + lane16) * 64
                                   + (((s * 4 + kl) ^ sw) * 8));
  }
  if constexpr (Q != 2) {
    constexpr int NF0 = (Q == 1) ? 2 : 0;
#pragma unroll
    for (int n = 0; n < 2; ++n)
#pragma unroll
      for (int s = 0; s < 2; ++s)
        bf2[n][s] = *(const f16x8*)(Bb + (wn * 64 + (NF0 + n) * 16 + lane16) * 64
                                    + (((s * 4 + kl) ^ sw) * 8));
  }
}
template<int Q>
__device__ __forceinline__ void phase_mm(f16x8 (&af)[4][2], f16x8 (&bf2)[2][2],
                                         f32x4 (&acc)[8][4]) {
  constexpr int MQ = (Q >> 1) * 4;
  constexpr int NF0 = (Q == 1 || Q == 2) ? 2 : 0;
#pragma unroll
  for (int m = 0; m < 4; ++m)
#pragma unroll
    for (int n = 0; n < 2; ++n)
#pragma unroll
      for (int s = 0; s < 2; ++s)
        acc[MQ + m][NF0 + n] = __builtin_amdgcn_mfma_f32_16x16x32_f16(
            af[m][s], bf2[n][s], acc[MQ + m][NF0 + n], 0, 0, 0);
}

#define FENCE() asm volatile("" ::: "memory")
#define BAR() __builtin_amdgcn_s_barrier()
#define VMW6() asm volatile("s_waitcnt vmcnt(6)" ::: "memory")
#define VMW4() asm volatile("s_waitcnt vmcnt(4)" ::: "memory")
#define VMW0() asm volatile("s_waitcnt vmcnt(0)" ::: "memory")

__global__ __launch_bounds__(512, 2) void gemm1_8ph(const u16* __restrict__ Xh,
    const u16* __restrict__ Eh, const float* __restrict__ xnorm,
    const float* __restrict__ enorm, float* __restrict__ D,
    float* __restrict__ S1p, float* __restrict__ STp, u16* __restrict__ Pu) {
  __shared__ __align__(16) u16 lds[2][2][256 * 64];  // 128 KB
  int bid = blockIdx.x;
  int s = (bid & 7) * 128 + (bid >> 3);   // XCD swizzle, bijective (1024 % 8 == 0)
  int rt = s >> 4, ct = s & 15;
  int n0 = rt << 8, k0 = ct << 8;
  int t = threadIdx.x;
  int l = t & 63, w = t >> 6;
  int wm = w >> 2, wn = w & 3;
  int lane16 = l & 15, kl = l >> 4;

  u16* lA0 = &lds[0][0][0]; u16* lB0 = &lds[0][1][0];
  u16* lA1 = &lds[1][0][0]; u16* lB1 = &lds[1][1][0];

  auto gA = [&](int kt) { return Xh + n0 * 512 + kt * 64; };
  auto gB = [&](int kt) { return Eh + k0 * 512 + kt * 64; };

  f32x4 acc[8][4];
#pragma unroll
  for (int m = 0; m < 8; ++m)
#pragma unroll
    for (int n = 0; n < 4; ++n) acc[m][n] = f32x4{0.f, 0.f, 0.f, 0.f};
  f16x8 af[4][2], bf2[2][2];

  stageA_g1(gA(0), lA0, 0, t);
  stageB_g1(gB(0), lB0, 1, t);
  stageB_g1(gB(0), lB0, 0, t);
  stageA_g1(gA(0), lA0, 1, t);
  stageA_g1(gA(1), lA1, 0, t);
  stageB_g1(gB(1), lB1, 1, t);
  VMW4();
  BAR();

#pragma unroll 1
  for (int i = 0; i < 4; ++i) {
    int ktO = 2 * i + 1;
    int ktE2 = 2 * i + 2, ktO2 = 2 * i + 3;
    bool more = (i < 3);
    phase_ld<0>(lA0, lB0, wm, wn, lane16, kl, af, bf2);
    stageB_g1(gB(ktO), lB1, 0, t);
    FENCE(); BAR();
    __builtin_amdgcn_s_setprio(1); phase_mm<0>(af, bf2, acc); __builtin_amdgcn_s_setprio(0);
    FENCE(); BAR();
    phase_ld<1>(lA0, lB0, wm, wn, lane16, kl, af, bf2);
    stageA_g1(gA(ktO), lA1, 1, t);
    FENCE(); BAR();
    __builtin_amdgcn_s_setprio(1); phase_mm<1>(af, bf2, acc); __builtin_amdgcn_s_setprio(0);
    FENCE(); BAR();
    phase_ld<2>(lA0, lB0, wm, wn, lane16, kl, af, bf2);
    if (more) stageA_g1(gA(ktE2), lA0, 0, t);
    FENCE(); BAR();
    __builtin_amdgcn_s_setprio(1); phase_mm<2>(af, bf2, acc); __builtin_amdgcn_s_setprio(0);
    FENCE(); BAR();
    phase_ld<3>(lA0, lB0, wm, wn, lane16, kl, af, bf2);
    if (more) stageB_g1(gB(ktE2), lB0, 1, t);
    FENCE(); BAR();
    __builtin_amdgcn_s_setprio(1); phase_mm<3>(af, bf2, acc); __builtin_amdgcn_s_setprio(0);
    if (i == 3) { VMW0(); } else { VMW4(); }
    BAR();
    phase_ld<0>(lA1, lB1, wm, wn, lane16, kl, af, bf2);
    if (more) stageB_g1(gB(ktE2), lB0, 0, t);
    FENCE(); BAR();
    __builtin_amdgcn_s_setprio(1); phase_mm<0>(af, bf2, acc); __builtin_amdgcn_s_setprio(0);
    FENCE(); BAR();
    phase_ld<1>(lA1, lB1, wm, wn, lane16, kl, af, bf2);
    if (more) stageA_g1(gA(ktE2), lA0, 1, t);
    FENCE(); BAR();
    __builtin_amdgcn_s_setprio(1); phase_mm<1>(af, bf2, acc); __builtin_amdgcn_s_setprio(0);
    FENCE(); BAR();
    phase_ld<2>(lA1, lB1, wm, wn, lane16, kl, af, bf2);
    if (more) stageA_g1(gA(ktO2), lA1, 0, t);
    FENCE(); BAR();
    __builtin_amdgcn_s_setprio(1); phase_mm<2>(af, bf2, acc); __builtin_amdgcn_s_setprio(0);
    FENCE(); BAR();
    phase_ld<3>(lA1, lB1, wm, wn, lane16, kl, af, bf2);
    if (more) stageB_g1(gB(ktO2), lB1, 1, t);
    FENCE(); BAR();
    __builtin_amdgcn_s_setprio(1); phase_mm<3>(af, bf2, acc); __builtin_amdgcn_s_setprio(0);
    if (more) { VMW4(); }
    BAR();
  }

  // epilogue: D = xnorm - l (cached; softmax reads next); Pu = bf16(exp(l)) NT
  float en[4];
#pragma unroll
  for (int nf = 0; nf < 4; ++nf) en[nf] = enorm[k0 + wn * 64 + nf * 16 + lane16];
  float* ldsS = (float*)&lds[0][0][0];   // [256][4]
  float* ldsT = ldsS + 1024;             // [256][4]
#pragma unroll
  for (int mf = 0; mf < 8; ++mf) {
#pragma unroll
    for (int r = 0; r < 4; ++r) {
      int lrow = wm * 128 + mf * 16 + kl * 4 + r;
      int row = n0 + lrow;
      float xv = xnorm[row];
      float lv[4], ev[4];
#pragma unroll
      for (int nf = 0; nf < 4; ++nf) lv[nf] = 2.0f * acc[mf][nf][r] - en[nf];
      float* Drow = D + (size_t)row * 4096 + k0 + wn * 64 + lane16;
#pragma unroll
      for (int nf = 0; nf < 4; ++nf) Drow[nf * 16] = xv - lv[nf];
#pragma unroll
      for (int nf = 0; nf < 4; ++nf) ev[nf] = __expf(lv[nf]);
      u32x2 pp;
      pp[0] = (uint32_t)f2b(ev[0]) | ((uint32_t)f2b(ev[1]) << 16);
      pp[1] = (uint32_t)f2b(ev[2]) | ((uint32_t)f2b(ev[3]) << 16);
      __builtin_nontemporal_store(pp,
          (u32x2*)(Pu + (size_t)row * 4096 + k0 + wn * 64 + lane16 * 4));
      float s1 = ev[0] + ev[1] + ev[2] + ev[3];
      float sT = __expf(lv[0] * INVT - CSH) + __expf(lv[1] * INVT - CSH)
               + __expf(lv[2] * INVT - CSH) + __expf(lv[3] * INVT - CSH);
#pragma unroll
      for (int o = 1; o < 16; o <<= 1) { s1 += __shfl_xor(s1, o); sT += __shfl_xor(sT, o); }
      if (lane16 == 0) { ldsS[lrow * 4 + wn] = s1; ldsT[lrow * 4 + wn] = sT; }
    }
  }
  __syncthreads();
  {
    int rr = t & 255;
    if (t < 256) {
      float v = ldsS[rr * 4 + 0] + ldsS[rr * 4 + 1] + ldsS[rr * 4 + 2] + ldsS[rr * 4 + 3];
      S1p[ct * 16384 + n0 + rr] = v;
    } else {
      float v = ldsT[rr * 4 + 0] + ldsT[rr * 4 + 1] + ldsT[rr * 4 + 2] + ldsT[rr * 4 + 3];
      STp[ct * 16384 + n0 + rr] = v;
    }
  }
}

// ------- softmax: combine T-partials + single D pass -> assign (NT stores) ----
__global__ __launch_bounds__(256) void softmax_out(const float* __restrict__ D,
    const float* __restrict__ xnorm, const float* __restrict__ STp,
    float* __restrict__ assign) {
  __shared__ float tt[128][33];
  int n0 = blockIdx.x << 5;
  int b = n0 >> 10, hw0 = n0 & 1023;
  int t = threadIdx.x;
  int i = t >> 3, jc = t & 7;
  int row = n0 + i;
  const float* Dr = D + (size_t)row * 4096;
  float sT = STp[(jc * 2) * 16384 + row] + STp[(jc * 2 + 1) * 16384 + row];
#pragma unroll
  for (int o = 1; o < 8; o <<= 1) sT += __shfl_xor(sT, o);
  float isT = 1.0f / sT;
  float xn = xnorm[row];

  float* assignB = assign + b * 4194304 + hw0;
  for (int kt = 0; kt < 32; ++kt) {
    int kb = kt << 7;
    for (int it = 0; it < 4; ++it) {
      int col4 = (jc + it * 8) * 4;
      float4 dv = *(const float4*)(Dr + kb + col4);
      float e0 = xn - dv.x, e1 = xn - dv.y, e2 = xn - dv.z, e3 = xn - dv.w;
      tt[col4 + 0][i] = __expf(e0 * INVT - CSH) * isT;
      tt[col4 + 1][i] = __expf(e1 * INVT - CSH) * isT;
      tt[col4 + 2][i] = __expf(e2 * INVT - CSH) * isT;
      tt[col4 + 3][i] = __expf(e3 * INVT - CSH) * isT;
    }
    __syncthreads();
    for (int idx = t; idx < 1024; idx += 256) {
      int j = idx >> 3, ic = idx & 7;
      f32x4 o;
      o[0] = tt[j][ic * 4 + 0]; o[1] = tt[j][ic * 4 + 1];
      o[2] = tt[j][ic * 4 + 2]; o[3] = tt[j][ic * 4 + 3];
      __builtin_nontemporal_store(o, (f32x4*)(assignB + (kb + j) * 1024 + ic * 4));
    }
    __syncthreads();
  }
}

// ===== GEMM2 (3-deep, 2-phase/tile, 16 MFMA/phase): 128(c) x 256(n), BK=64 ====
// q^T = Et . Pu^T scaled by 1/s1[col] (summed from S1p) at epilogue.
// 3 LDS buffers: staged buffer is always a full tile away from the read buffer,
// so stage placement within the 2 phases is unconstrained. vmcnt(6) per tile.
__device__ __forceinline__ void stageA2(const u16* __restrict__ g, u16* l, int h, int t) {
  int ri = t >> 3, ch = t & 7;
  int r = (ri >> 5) * 64 + h * 32 + (ri & 31);
  g2l16(g + (size_t)r * 4096 + ((ch ^ (r & 7)) * 8), l + r * 64 + ch * 8);
}
__device__ __forceinline__ void stageB2(const u16* __restrict__ g, u16* l, int h, int j, int t) {
  int ri = j * 64 + (t >> 3), ch = t & 7;
  int r = (ri >> 5) * 64 + h * 32 + (ri & 31);
  g2l16(g + (size_t)r * 4096 + ((ch ^ (r & 7)) * 8), l + r * 64 + ch * 8);
}

template<int P>
__device__ __forceinline__ void phase_ldN(const u16* Ab, const u16* Bb,
    int wm, int wn, int lane16, int kl, bf16x8 (&af)[2][2], bf16x8 (&bf)[4][2]) {
  int sw = lane16 & 7;
#pragma unroll
  for (int m = 0; m < 2; ++m)
#pragma unroll
    for (int s = 0; s < 2; ++s)
      af[m][s] = *(const bf16x8*)(Ab + (wm * 64 + (P * 2 + m) * 16 + lane16) * 64
                                  + (((s * 4 + kl) ^ sw) * 8));
  if constexpr (P == 0) {
#pragma unroll
    for (int n = 0; n < 4; ++n)
#pragma unroll
      for (int s = 0; s < 2; ++s)
        bf[n][s] = *(const bf16x8*)(Bb + (wn * 64 + n * 16 + lane16) * 64
                                    + (((s * 4 + kl) ^ sw) * 8));
  }
}
template<int P>
__device__ __forceinline__ void phase_mmN(bf16x8 (&af)[2][2], bf16x8 (&bf)[4][2],
                                          f32x4 (&acc)[4][4]) {
#pragma unroll
  for (int m = 0; m < 2; ++m)
#pragma unroll
    for (int n = 0; n < 4; ++n)
#pragma unroll
      for (int s = 0; s < 2; ++s)
        acc[P * 2 + m][n] = __builtin_amdgcn_mfma_f32_16x16x32_bf16(
            af[m][s], bf[n][s], acc[P * 2 + m][n], 0, 0, 0);
}

// one K-tile: 2 phases x 16 MFMA; stage tile kn into (An,Bn) if ST
#define G2_TILE(Ab, Bb, An, Bn, kn, ST, LASTW) \
  { const u16* gAn = gA + (kn) * 64; const u16* gBn = gB + (kn) * 64; \
    phase_ldN<0>(Ab, Bb, wm, wn, lane16, kl, af, bf); \
    if (ST) { stageA2(gAn, An, 0, t); stageA2(gAn, An, 1, t); } \
    FENCE(); BAR(); \
    __builtin_amdgcn_s_setprio(1); phase_mmN<0>(af, bf, acc); __builtin_amdgcn_s_setprio(0); \
    FENCE(); BAR(); \
    phase_ldN<1>(Ab, Bb, wm, wn, lane16, kl, af, bf); \
    if (ST) { stageB2(gBn, Bn, 0, 0, t); stageB2(gBn, Bn, 0, 1, t); \
              stageB2(gBn, Bn, 1, 0, t); stageB2(gBn, Bn, 1, 1, t); } \
    FENCE(); BAR(); \
    __builtin_amdgcn_s_setprio(1); phase_mmN<1>(af, bf, acc); __builtin_amdgcn_s_setprio(0); \
    if (!(LASTW)) { if (ST) { VMW6(); } else { VMW0(); } BAR(); } }

__global__ __launch_bounds__(512, 1) void gemm2_3d(const u16* __restrict__ Et,
    const u16* __restrict__ Pu, const float* __restrict__ S1p, float* __restrict__ Q) {
  __shared__ __align__(16) u16 lds[3][384 * 64];  // 3 x (A 16KB + B 32KB) = 144 KB
  int bid = blockIdx.x;
  int s = (bid & 7) * 32 + (bid >> 3);   // 256 blocks, bijective XCD swizzle
  int ct = s >> 2, rt = s & 3;           // 4 c-blocks of an n-panel share an XCD
  int c0 = rt << 7, n0 = ct << 8;
  int t = threadIdx.x;
  int l = t & 63, w = t >> 6;
  int wm = w >> 2, wn = w & 3;
  int lane16 = l & 15, kl = l >> 4;

  u16* A0 = &lds[0][0]; u16* B0 = &lds[0][128 * 64];
  u16* A1 = &lds[1][0]; u16* B1 = &lds[1][128 * 64];
  u16* A2 = &lds[2][0]; u16* B2 = &lds[2][128 * 64];

  const u16* gA = Et + (size_t)c0 * 4096;
  const u16* gB = Pu + (size_t)n0 * 4096;

  f32x4 acc[4][4];
#pragma unroll
  for (int m = 0; m < 4; ++m)
#pragma unroll
    for (int n = 0; n < 4; ++n) acc[m][n] = f32x4{0.f, 0.f, 0.f, 0.f};
  bf16x8 af[2][2], bf[4][2];

  // prologue: tiles 0 (buf0) and 1 (buf1), 12 loads; wait tile0 (6 may remain)
  stageA2(gA + 0 * 64, A0, 0, t); stageA2(gA + 0 * 64, A0, 1, t);
  stageB2(gB + 0 * 64, B0, 0, 0, t); stageB2(gB + 0 * 64, B0, 0, 1, t);
  stageB2(gB + 0 * 64, B0, 1, 0, t); stageB2(gB + 0 * 64, B0, 1, 1, t);
  stageA2(gA + 1 * 64, A1, 0, t); stageA2(gA + 1 * 64, A1, 1, t);
  stageB2(gB + 1 * 64, B1, 0, 0, t); stageB2(gB + 1 * 64, B1, 0, 1, t);
  stageB2(gB + 1 * 64, B1, 1, 0, t); stageB2(gB + 1 * 64, B1, 1, 1, t);
  VMW6();
  BAR();

#pragma unroll 1
  for (int j = 0; j < 20; ++j) {
    int kt = 3 * j;
    G2_TILE(A0, B0, A2, B2, kt + 2, 1, 0);   // tile kt   -> stage kt+2 (buf2)
    G2_TILE(A1, B1, A0, B0, kt + 3, 1, 0);   // tile kt+1 -> stage kt+3 (buf0)
    G2_TILE(A2, B2, A1, B1, kt + 4, 1, 0);   // tile kt+2 -> stage kt+4 (buf1)
  }
  // tiles 60..63
  G2_TILE(A0, B0, A2, B2, 62, 1, 0);         // tile 60 -> stage 62 (buf2)
  G2_TILE(A1, B1, A0, B0, 63, 1, 0);         // tile 61 -> stage 63 (buf0)
  G2_TILE(A2, B2, A1, B1, 0, 0, 0);          // tile 62, no stage, VMW0
  G2_TILE(A0, B0, A1, B1, 0, 0, 1);          // tile 63, last

  // epilogue: invs1 from S1p partials (L2-resident), then scaled NT store
  float iv[4];
#pragma unroll
  for (int nn = 0; nn < 4; ++nn) {
    int col = n0 + wn * 64 + nn * 16 + lane16;
    float ssum = 0.f;
#pragma unroll
    for (int j = 0; j < 16; ++j) ssum += S1p[j * 16384 + col];
    iv[nn] = 1.0f / ssum;
  }
  for (int m = 0; m < 4; ++m) {
    for (int r = 0; r < 4; ++r) {
      int crow = c0 + wm * 64 + m * 16 + kl * 4 + r;
      for (int nn = 0; nn < 4; ++nn) {
        int col = n0 + wn * 64 + nn * 16 + lane16;
        int bb = col >> 10, hw = col & 1023;
        __builtin_nontemporal_store(acc[m][nn][r] * iv[nn],
                                    &Q[bb * 524288 + crow * 1024 + hw]);
      }
    }
  }
}

extern "C" void kernel_launch(void* const* d_in, const int* in_sizes, int n_in,
                              void* d_out, int out_size, void* d_ws, size_t ws_size,
                              hipStream_t stream) {
  const float* feat = (const float*)d_in[0];   // (16, 512, 32, 32)
  const float* cb = (const float*)d_in[1];     // (4096, 512)
  float* out = (float*)d_out;
  float* q_out = out;                          // 8388608
  float* a_out = out + 8388608;                // 67108864
  float* d_dist = out + 75497472;              // 67108864

  char* ws = (char*)d_ws;
  u16* Xh = (u16*)(ws + 0);                    // 16 MB  fp16 X (n,c)
  u16* Eh = (u16*)(ws + 16777216);             // 4 MB   fp16 E (k,c)
  u16* Et = (u16*)(ws + 20971520);             // 4 MB   bf16 E^T (c,k) pi-order
  float* xnorm = (float*)(ws + 25165824);      // 64 KB
  float* enorm = (float*)(ws + 25231360);      // 16 KB
  float* S1p = (float*)(ws + 25247744);        // 1 MB  [16][16384]
  float* STp = (float*)(ws + 26296320);        // 1 MB
  u16* Pu = (u16*)(ws + 27410432);             // 128 MB -> ends ~155 MB

  prep_all<<<320, 256, 0, stream>>>(feat, cb, Xh, xnorm, Eh, enorm, Et);
  gemm1_8ph<<<1024, 512, 0, stream>>>(Xh, Eh, xnorm, enorm, d_dist, S1p, STp, Pu);
  softmax_out<<<512, 256, 0, stream>>>(d_dist, xnorm, STp, a_out);   // D L3-warm
  gemm2_3d<<<256, 512, 0, stream>>>(Et, Pu, S1p, q_out);
}

// Round 15
// 330.907 us; speedup vs baseline: 1.1441x; 1.0156x over previous
//
#include <hip/hip_runtime.h>
#include <hip/hip_bf16.h>
#include <stdint.h>

typedef unsigned short u16;
typedef _Float16 f16;
typedef f16 f16x8 __attribute__((ext_vector_type(8)));
typedef __bf16 bf16x8 __attribute__((ext_vector_type(8)));
typedef float f32x4 __attribute__((ext_vector_type(4)));
typedef uint32_t u32x2 __attribute__((ext_vector_type(2)));

#define INVT 14.2857142857142857f  // 1/0.07
#define CSH  32.0f                 // extra shift on T-path exponents (softmax-invariant)

__device__ __forceinline__ u16 f2b(float f) {
  __hip_bfloat16 h = __float2bfloat16(f);
  return __builtin_bit_cast(u16, h);
}
__device__ __forceinline__ u16 f2h(float f) {
  f16 h = (f16)f;
  return __builtin_bit_cast(u16, h);
}
__device__ __forceinline__ void g2l16(const void* g, void* l) {
  __builtin_amdgcn_global_load_lds(
      (__attribute__((address_space(1))) void*)(uintptr_t)g,
      (__attribute__((address_space(3))) void*)(uint32_t)(uintptr_t)l, 16, 0, 0);
}

// ---- merged prep: blocks 0..255 do feat->Xh/xnorm; 256..319 do cb->Eh/enorm/Et
// Et stored with per-64-chunk column permutation pi (position 4l+nf = k 16nf+l);
// gemm1 writes Pu in the same pi order, so pi cancels in gemm2's contraction.
__global__ __launch_bounds__(256) void prep_all(const float* __restrict__ feat,
    const float* __restrict__ cb, u16* __restrict__ Xh, float* __restrict__ xnorm,
    u16* __restrict__ Eh, float* __restrict__ enorm, u16* __restrict__ Et) {
  __shared__ __align__(16) char smraw[16640];
  int t = threadIdx.x;
  if (blockIdx.x < 256) {
    float (*sm)[65] = (float(*)[65])smraw;
    int b = blockIdx.x >> 4;
    int hw0 = (blockIdx.x & 15) << 6;
    int hwi = t & 63, ci0 = t >> 6;
    float xs2[2] = {0.f, 0.f};
    int cj = t & 7;
    for (int c0 = 0; c0 < 512; c0 += 64) {
      for (int ci = ci0; ci < 64; ci += 4)
        sm[ci][hwi] = feat[((b * 512 + c0 + ci) << 10) + hw0 + hwi];
      __syncthreads();
      for (int w = 0; w < 2; ++w) {
        int hj = (t >> 3) + (w << 5);
        int n = (b << 10) + hw0 + hj;
        uint32_t hp[4];
        for (int p = 0; p < 4; ++p) {
          float v0 = sm[cj * 8 + p * 2 + 0][hj];
          float v1 = sm[cj * 8 + p * 2 + 1][hj];
          xs2[w] += v0 * v0 + v1 * v1;
          hp[p] = (uint32_t)f2h(v0) | ((uint32_t)f2h(v1) << 16);
        }
        *(uint4*)(Xh + n * 512 + c0 + cj * 8) = make_uint4(hp[0], hp[1], hp[2], hp[3]);
      }
      __syncthreads();
    }
    for (int w = 0; w < 2; ++w) {
      float v = xs2[w];
      v += __shfl_xor(v, 1); v += __shfl_xor(v, 2); v += __shfl_xor(v, 4);
      if (cj == 0) {
        int hj = (t >> 3) + (w << 5);
        xnorm[(b << 10) + hw0 + hj] = v;
      }
    }
  } else {
    u16 (*sm)[72] = (u16(*)[72])smraw;
    int k0 = (blockIdx.x - 256) << 6;
    int kr = t >> 2, q = t & 3;
    float nrm = 0.f;
    for (int c0 = 0; c0 < 512; c0 += 64) {
      const float4* src = (const float4*)(cb + (size_t)(k0 + kr) * 512 + c0 + q * 16);
      float4 v[4];
      uint32_t hw_[8], bw[8];
#pragma unroll
      for (int p = 0; p < 4; ++p) {
        v[p] = src[p];
        nrm += v[p].x * v[p].x + v[p].y * v[p].y + v[p].z * v[p].z + v[p].w * v[p].w;
        hw_[p * 2 + 0] = (uint32_t)f2h(v[p].x) | ((uint32_t)f2h(v[p].y) << 16);
        hw_[p * 2 + 1] = (uint32_t)f2h(v[p].z) | ((uint32_t)f2h(v[p].w) << 16);
        bw[p * 2 + 0] = (uint32_t)f2b(v[p].x) | ((uint32_t)f2b(v[p].y) << 16);
        bw[p * 2 + 1] = (uint32_t)f2b(v[p].z) | ((uint32_t)f2b(v[p].w) << 16);
      }
      uint4* dstE = (uint4*)(Eh + (size_t)(k0 + kr) * 512 + c0 + q * 16);
      dstE[0] = make_uint4(hw_[0], hw_[1], hw_[2], hw_[3]);
      dstE[1] = make_uint4(hw_[4], hw_[5], hw_[6], hw_[7]);
      uint4* dstS = (uint4*)&sm[kr][q * 16];
      dstS[0] = make_uint4(bw[0], bw[1], bw[2], bw[3]);
      dstS[1] = make_uint4(bw[4], bw[5], bw[6], bw[7]);
      __syncthreads();
      int ci = t >> 2;
      uint32_t o[8];
#pragma unroll
      for (int j = 0; j < 8; ++j) {
        int jj0 = 2 * j, jj1 = 2 * j + 1;
        u16 a0 = sm[16 * (jj0 & 3) + q * 4 + (jj0 >> 2)][ci];
        u16 a1 = sm[16 * (jj1 & 3) + q * 4 + (jj1 >> 2)][ci];
        o[j] = (uint32_t)a0 | ((uint32_t)a1 << 16);
      }
      uint4* dstT = (uint4*)(Et + (size_t)(c0 + ci) * 4096 + k0 + q * 16);
      dstT[0] = make_uint4(o[0], o[1], o[2], o[3]);
      dstT[1] = make_uint4(o[4], o[5], o[6], o[7]);
      __syncthreads();
    }
    nrm += __shfl_xor(nrm, 1); nrm += __shfl_xor(nrm, 2);
    if (q == 0) enorm[k0 + kr] = nrm;
  }
}

// ============ GEMM1 (fp16): 256x256 tile, BK=64, 8 waves, 8-phase =============
__device__ __forceinline__ void stageA_g1(const u16* __restrict__ g, u16* l, int h, int t) {
  int r0 = t >> 3, c = ((t & 7) ^ (r0 & 7)) * 8, cw = (t & 7) * 8;
  int ra = h * 64 + r0, rb = 128 + h * 64 + r0;
  g2l16(g + ra * 512 + c, l + ra * 64 + cw);
  g2l16(g + rb * 512 + c, l + rb * 64 + cw);
}
__device__ __forceinline__ void stageB_g1(const u16* __restrict__ g, u16* l, int hb, int t) {
  int r0 = t >> 3, c = ((t & 7) ^ (r0 & 7)) * 8, cw = (t & 7) * 8;
  int ra = (r0 >> 5) * 64 + hb * 32 + (r0 & 31);
  int rb = ((r0 + 64) >> 5) * 64 + hb * 32 + (r0 & 31);
  g2l16(g + ra * 512 + c, l + ra * 64 + cw);
  g2l16(g + rb * 512 + c, l + rb * 64 + cw);
}

template<int Q>
__device__ __forceinline__ void phase_ld(const u16* Ab, const u16* Bb,
    int wm, int wn, int lane16, int kl, f16x8 (&af)[4][2], f16x8 (&bf2)[2][2]) {
  int sw = lane16 & 7;
  if constexpr (Q == 0 || Q == 2) {
#pragma unroll
    for (int m = 0; m < 4; ++m)
#pragma unroll
      for (int s = 0; s < 2; ++s)
        af[m][s] = *(const f16x8*)(Ab + (wm * 128 + ((Q >> 1) * 4 + m) * 16 + lane16) * 64
                                   + (((s * 4 + kl) ^ sw) * 8));
  }
  if constexpr (Q != 2) {
    constexpr int NF0 = (Q == 1) ? 2 : 0;
#pragma unroll
    for (int n = 0; n < 2; ++n)
#pragma unroll
      for (int s = 0; s < 2; ++s)
        bf2[n][s] = *(const f16x8*)(Bb + (wn * 64 + (NF0 + n) * 16 + lane16) * 64
                                    + (((s * 4 + kl) ^ sw) * 8));
  }
}
template<int Q>
__device__ __forceinline__ void phase_mm(f16x8 (&af)[4][2], f16x8 (&bf2)[2][2],
                                         f32x4 (&acc)[8][4]) {
  constexpr int MQ = (Q >> 1) * 4;
  constexpr int NF0 = (Q == 1 || Q == 2) ? 2 : 0;
#pragma unroll
  for (int m = 0; m < 4; ++m)
#pragma unroll
    for (int n = 0; n < 2; ++n)
#pragma unroll
      for (int s = 0; s < 2; ++s)
        acc[MQ + m][NF0 + n] = __builtin_amdgcn_mfma_f32_16x16x32_f16(
            af[m][s], bf2[n][s], acc[MQ + m][NF0 + n], 0, 0, 0);
}

#define FENCE() asm volatile("" ::: "memory")
#define BAR() __builtin_amdgcn_s_barrier()
#define VMW6() asm volatile("s_waitcnt vmcnt(6)" ::: "memory")
#define VMW4() asm volatile("s_waitcnt vmcnt(4)" ::: "memory")
#define VMW0() asm volatile("s_waitcnt vmcnt(0)" ::: "memory")

__global__ __launch_bounds__(512, 2) void gemm1_8ph(const u16* __restrict__ Xh,
    const u16* __restrict__ Eh, const float* __restrict__ xnorm,
    const float* __restrict__ enorm, float* __restrict__ D,
    float* __restrict__ S1p, float* __restrict__ STp, u16* __restrict__ Pu) {
  __shared__ __align__(16) u16 lds[2][2][256 * 64];  // 128 KB
  int bid = blockIdx.x;
  int s = (bid & 7) * 128 + (bid >> 3);   // XCD swizzle, bijective (1024 % 8 == 0)
  int rt = s >> 4, ct = s & 15;
  int n0 = rt << 8, k0 = ct << 8;
  int t = threadIdx.x;
  int l = t & 63, w = t >> 6;
  int wm = w >> 2, wn = w & 3;
  int lane16 = l & 15, kl = l >> 4;

  u16* lA0 = &lds[0][0][0]; u16* lB0 = &lds[0][1][0];
  u16* lA1 = &lds[1][0][0]; u16* lB1 = &lds[1][1][0];

  auto gA = [&](int kt) { return Xh + n0 * 512 + kt * 64; };
  auto gB = [&](int kt) { return Eh + k0 * 512 + kt * 64; };

  f32x4 acc[8][4];
#pragma unroll
  for (int m = 0; m < 8; ++m)
#pragma unroll
    for (int n = 0; n < 4; ++n) acc[m][n] = f32x4{0.f, 0.f, 0.f, 0.f};
  f16x8 af[4][2], bf2[2][2];

  stageA_g1(gA(0), lA0, 0, t);
  stageB_g1(gB(0), lB0, 1, t);
  stageB_g1(gB(0), lB0, 0, t);
  stageA_g1(gA(0), lA0, 1, t);
  stageA_g1(gA(1), lA1, 0, t);
  stageB_g1(gB(1), lB1, 1, t);
  VMW4();
  BAR();

#pragma unroll 1
  for (int i = 0; i < 4; ++i) {
    int ktO = 2 * i + 1;
    int ktE2 = 2 * i + 2, ktO2 = 2 * i + 3;
    bool more = (i < 3);
    phase_ld<0>(lA0, lB0, wm, wn, lane16, kl, af, bf2);
    stageB_g1(gB(ktO), lB1, 0, t);
    FENCE(); BAR();
    __builtin_amdgcn_s_setprio(1); phase_mm<0>(af, bf2, acc); __builtin_amdgcn_s_setprio(0);
    FENCE(); BAR();
    phase_ld<1>(lA0, lB0, wm, wn, lane16, kl, af, bf2);
    stageA_g1(gA(ktO), lA1, 1, t);
    FENCE(); BAR();
    __builtin_amdgcn_s_setprio(1); phase_mm<1>(af, bf2, acc); __builtin_amdgcn_s_setprio(0);
    FENCE(); BAR();
    phase_ld<2>(lA0, lB0, wm, wn, lane16, kl, af, bf2);
    if (more) stageA_g1(gA(ktE2), lA0, 0, t);
    FENCE(); BAR();
    __builtin_amdgcn_s_setprio(1); phase_mm<2>(af, bf2, acc); __builtin_amdgcn_s_setprio(0);
    FENCE(); BAR();
    phase_ld<3>(lA0, lB0, wm, wn, lane16, kl, af, bf2);
    if (more) stageB_g1(gB(ktE2), lB0, 1, t);
    FENCE(); BAR();
    __builtin_amdgcn_s_setprio(1); phase_mm<3>(af, bf2, acc); __builtin_amdgcn_s_setprio(0);
    if (i == 3) { VMW0(); } else { VMW4(); }
    BAR();
    phase_ld<0>(lA1, lB1, wm, wn, lane16, kl, af, bf2);
    if (more) stageB_g1(gB(ktE2), lB0, 0, t);
    FENCE(); BAR();
    __builtin_amdgcn_s_setprio(1); phase_mm<0>(af, bf2, acc); __builtin_amdgcn_s_setprio(0);
    FENCE(); BAR();
    phase_ld<1>(lA1, lB1, wm, wn, lane16, kl, af, bf2);
    if (more) stageA_g1(gA(ktE2), lA0, 1, t);
    FENCE(); BAR();
    __builtin_amdgcn_s_setprio(1); phase_mm<1>(af, bf2, acc); __builtin_amdgcn_s_setprio(0);
    FENCE(); BAR();
    phase_ld<2>(lA1, lB1, wm, wn, lane16, kl, af, bf2);
    if (more) stageA_g1(gA(ktO2), lA1, 0, t);
    FENCE(); BAR();
    __builtin_amdgcn_s_setprio(1); phase_mm<2>(af, bf2, acc); __builtin_amdgcn_s_setprio(0);
    FENCE(); BAR();
    phase_ld<3>(lA1, lB1, wm, wn, lane16, kl, af, bf2);
    if (more) stageB_g1(gB(ktO2), lB1, 1, t);
    FENCE(); BAR();
    __builtin_amdgcn_s_setprio(1); phase_mm<3>(af, bf2, acc); __builtin_amdgcn_s_setprio(0);
    if (more) { VMW4(); }
    BAR();
  }

  // epilogue: D = xnorm - l (cached; softmax reads next); Pu = bf16(exp(l)) NT
  float en[4];
#pragma unroll
  for (int nf = 0; nf < 4; ++nf) en[nf] = enorm[k0 + wn * 64 + nf * 16 + lane16];
  float* ldsS = (float*)&lds[0][0][0];   // [256][4]
  float* ldsT = ldsS + 1024;             // [256][4]
#pragma unroll
  for (int mf = 0; mf < 8; ++mf) {
#pragma unroll
    for (int r = 0; r < 4; ++r) {
      int lrow = wm * 128 + mf * 16 + kl * 4 + r;
      int row = n0 + lrow;
      float xv = xnorm[row];
      float lv[4], ev[4];
#pragma unroll
      for (int nf = 0; nf < 4; ++nf) lv[nf] = 2.0f * acc[mf][nf][r] - en[nf];
      float* Drow = D + (size_t)row * 4096 + k0 + wn * 64 + lane16;
#pragma unroll
      for (int nf = 0; nf < 4; ++nf) Drow[nf * 16] = xv - lv[nf];
#pragma unroll
      for (int nf = 0; nf < 4; ++nf) ev[nf] = __expf(lv[nf]);
      u32x2 pp;
      pp[0] = (uint32_t)f2b(ev[0]) | ((uint32_t)f2b(ev[1]) << 16);
      pp[1] = (uint32_t)f2b(ev[2]) | ((uint32_t)f2b(ev[3]) << 16);
      __builtin_nontemporal_store(pp,
          (u32x2*)(Pu + (size_t)row * 4096 + k0 + wn * 64 + lane16 * 4));
      float s1 = ev[0] + ev[1] + ev[2] + ev[3];
      float sT = __expf(lv[0] * INVT - CSH) + __expf(lv[1] * INVT - CSH)
               + __expf(lv[2] * INVT - CSH) + __expf(lv[3] * INVT - CSH);
#pragma unroll
      for (int o = 1; o < 16; o <<= 1) { s1 += __shfl_xor(s1, o); sT += __shfl_xor(sT, o); }
      if (lane16 == 0) { ldsS[lrow * 4 + wn] = s1; ldsT[lrow * 4 + wn] = sT; }
    }
  }
  __syncthreads();
  {
    int rr = t & 255;
    if (t < 256) {
      float v = ldsS[rr * 4 + 0] + ldsS[rr * 4 + 1] + ldsS[rr * 4 + 2] + ldsS[rr * 4 + 3];
      S1p[ct * 16384 + n0 + rr] = v;
    } else {
      float v = ldsT[rr * 4 + 0] + ldsT[rr * 4 + 1] + ldsT[rr * 4 + 2] + ldsT[rr * 4 + 3];
      STp[ct * 16384 + n0 + rr] = v;
    }
  }
}

// ------- softmax v3: 128 rows x 2048 cols per block, big-tile transpose -------
// 256 blocks x 512 threads; LDS 128x132 fp32 (66 KB). 8x fewer barriers/byte and
// 512 B-contiguous NT stores vs v2. Adjacent bids (kh=0/1) share D rows -> L2.
__global__ __launch_bounds__(512) void softmax_out(const float* __restrict__ D,
    const float* __restrict__ xnorm, const float* __restrict__ STp,
    float* __restrict__ assign) {
  __shared__ float tt[128][132];
  int bid = blockIdx.x;
  int ng = bid >> 1, kh = bid & 1;
  int n0 = ng << 7;
  int b = n0 >> 10, hw0 = n0 & 1023;
  int t = threadIdx.x;
  int i = t >> 2, jc = t & 3;   // row 0..127, col-lane 0..3
  int row = n0 + i;
  float sT = 0.f;
#pragma unroll
  for (int p = 0; p < 4; ++p) sT += STp[(jc * 4 + p) * 16384 + row];
  sT += __shfl_xor(sT, 1); sT += __shfl_xor(sT, 2);
  float isT = 1.0f / sT;
  float xn = xnorm[row];
  int kbase = kh << 11;
  const float* Dr = D + (size_t)row * 4096 + kbase;
  float* assignB = assign + (size_t)b * 4194304 + hw0;

  for (int kt = 0; kt < 16; ++kt) {
    int kb = kt << 7;
#pragma unroll
    for (int it = 0; it < 8; ++it) {
      int col4 = it * 16 + jc * 4;
      float4 dv = *(const float4*)(Dr + kb + col4);
      tt[col4 + 0][i] = __expf((xn - dv.x) * INVT - CSH) * isT;
      tt[col4 + 1][i] = __expf((xn - dv.y) * INVT - CSH) * isT;
      tt[col4 + 2][i] = __expf((xn - dv.z) * INVT - CSH) * isT;
      tt[col4 + 3][i] = __expf((xn - dv.w) * INVT - CSH) * isT;
    }
    __syncthreads();
#pragma unroll
    for (int p = 0; p < 8; ++p) {
      int idx = t + (p << 9);          // 0..4095
      int j = idx >> 5, ic = idx & 31; // col j, hw chunk ic
      f32x4 o;
      o[0] = tt[j][ic * 4 + 0]; o[1] = tt[j][ic * 4 + 1];
      o[2] = tt[j][ic * 4 + 2]; o[3] = tt[j][ic * 4 + 3];
      __builtin_nontemporal_store(o,
          (f32x4*)(assignB + (size_t)(kbase + kb + j) * 1024 + ic * 4));
    }
    __syncthreads();
  }
}

// ===== GEMM2 (3-deep, 2-phase/tile, 16 MFMA/phase): 128(c) x 256(n), BK=64 ====
__device__ __forceinline__ void stageA2(const u16* __restrict__ g, u16* l, int h, int t) {
  int ri = t >> 3, ch = t & 7;
  int r = (ri >> 5) * 64 + h * 32 + (ri & 31);
  g2l16(g + (size_t)r * 4096 + ((ch ^ (r & 7)) * 8), l + r * 64 + ch * 8);
}
__device__ __forceinline__ void stageB2(const u16* __restrict__ g, u16* l, int h, int j, int t) {
  int ri = j * 64 + (t >> 3), ch = t & 7;
  int r = (ri >> 5) * 64 + h * 32 + (ri & 31);
  g2l16(g + (size_t)r * 4096 + ((ch ^ (r & 7)) * 8), l + r * 64 + ch * 8);
}

template<int P>
__device__ __forceinline__ void phase_ldN(const u16* Ab, const u16* Bb,
    int wm, int wn, int lane16, int kl, bf16x8 (&af)[2][2], bf16x8 (&bf)[4][2]) {
  int sw = lane16 & 7;
#pragma unroll
  for (int m = 0; m < 2; ++m)
#pragma unroll
    for (int s = 0; s < 2; ++s)
      af[m][s] = *(const bf16x8*)(Ab + (wm * 64 + (P * 2 + m) * 16 + lane16) * 64
                                  + (((s * 4 + kl) ^ sw) * 8));
  if constexpr (P == 0) {
#pragma unroll
    for (int n = 0; n < 4; ++n)
#pragma unroll
      for (int s = 0; s < 2; ++s)
        bf[n][s] = *(const bf16x8*)(Bb + (wn * 64 + n * 16 + lane16) * 64
                                    + (((s * 4 + kl) ^ sw) * 8));
  }
}
template<int P>
__device__ __forceinline__ void phase_mmN(bf16x8 (&af)[2][2], bf16x8 (&bf)[4][2],
                                          f32x4 (&acc)[4][4]) {
#pragma unroll
  for (int m = 0; m < 2; ++m)
#pragma unroll
    for (int n = 0; n < 4; ++n)
#pragma unroll
      for (int s = 0; s < 2; ++s)
        acc[P * 2 + m][n] = __builtin_amdgcn_mfma_f32_16x16x32_bf16(
            af[m][s], bf[n][s], acc[P * 2 + m][n], 0, 0, 0);
}

// one K-tile: 2 phases x 16 MFMA; stage tile kn into (An,Bn) if ST
#define G2_TILE(Ab, Bb, An, Bn, kn, ST, LASTW) \
  { const u16* gAn = gA + (kn) * 64; const u16* gBn = gB + (kn) * 64; \
    phase_ldN<0>(Ab, Bb, wm, wn, lane16, kl, af, bf); \
    if (ST) { stageA2(gAn, An, 0, t); stageA2(gAn, An, 1, t); } \
    FENCE(); BAR(); \
    __builtin_amdgcn_s_setprio(1); phase_mmN<0>(af, bf, acc); __builtin_amdgcn_s_setprio(0); \
    FENCE(); BAR(); \
    phase_ldN<1>(Ab, Bb, wm, wn, lane16, kl, af, bf); \
    if (ST) { stageB2(gBn, Bn, 0, 0, t); stageB2(gBn, Bn, 0, 1, t); \
              stageB2(gBn, Bn, 1, 0, t); stageB2(gBn, Bn, 1, 1, t); } \
    FENCE(); BAR(); \
    __builtin_amdgcn_s_setprio(1); phase_mmN<1>(af, bf, acc); __builtin_amdgcn_s_setprio(0); \
    if (!(LASTW)) { if (ST) { VMW6(); } else { VMW0(); } BAR(); } }

__global__ __launch_bounds__(512, 1) void gemm2_3d(const u16* __restrict__ Et,
    const u16* __restrict__ Pu, const float* __restrict__ S1p, float* __restrict__ Q) {
  __shared__ __align__(16) u16 lds[3][384 * 64];  // 3 x (A 16KB + B 32KB) = 144 KB
  int bid = blockIdx.x;
  int s = (bid & 7) * 32 + (bid >> 3);   // 256 blocks, bijective XCD swizzle
  int ct = s >> 2, rt = s & 3;           // 4 c-blocks of an n-panel share an XCD
  int c0 = rt << 7, n0 = ct << 8;
  int t = threadIdx.x;
  int l = t & 63, w = t >> 6;
  int wm = w >> 2, wn = w & 3;
  int lane16 = l & 15, kl = l >> 4;

  u16* A0 = &lds[0][0]; u16* B0 = &lds[0][128 * 64];
  u16* A1 = &lds[1][0]; u16* B1 = &lds[1][128 * 64];
  u16* A2 = &lds[2][0]; u16* B2 = &lds[2][128 * 64];

  const u16* gA = Et + (size_t)c0 * 4096;
  const u16* gB = Pu + (size_t)n0 * 4096;

  f32x4 acc[4][4];
#pragma unroll
  for (int m = 0; m < 4; ++m)
#pragma unroll
    for (int n = 0; n < 4; ++n) acc[m][n] = f32x4{0.f, 0.f, 0.f, 0.f};
  bf16x8 af[2][2], bf[4][2];

  // prologue: tiles 0 (buf0) and 1 (buf1), 12 loads; wait tile0 (6 may remain)
  stageA2(gA + 0 * 64, A0, 0, t); stageA2(gA + 0 * 64, A0, 1, t);
  stageB2(gB + 0 * 64, B0, 0, 0, t); stageB2(gB + 0 * 64, B0, 0, 1, t);
  stageB2(gB + 0 * 64, B0, 1, 0, t); stageB2(gB + 0 * 64, B0, 1, 1, t);
  stageA2(gA + 1 * 64, A1, 0, t); stageA2(gA + 1 * 64, A1, 1, t);
  stageB2(gB + 1 * 64, B1, 0, 0, t); stageB2(gB + 1 * 64, B1, 0, 1, t);
  stageB2(gB + 1 * 64, B1, 1, 0, t); stageB2(gB + 1 * 64, B1, 1, 1, t);
  VMW6();
  BAR();

#pragma unroll 1
  for (int j = 0; j < 20; ++j) {
    int kt = 3 * j;
    G2_TILE(A0, B0, A2, B2, kt + 2, 1, 0);   // tile kt   -> stage kt+2 (buf2)
    G2_TILE(A1, B1, A0, B0, kt + 3, 1, 0);   // tile kt+1 -> stage kt+3 (buf0)
    G2_TILE(A2, B2, A1, B1, kt + 4, 1, 0);   // tile kt+2 -> stage kt+4 (buf1)
  }
  // tiles 60..63
  G2_TILE(A0, B0, A2, B2, 62, 1, 0);         // tile 60 -> stage 62 (buf2)
  G2_TILE(A1, B1, A0, B0, 63, 1, 0);         // tile 61 -> stage 63 (buf0)
  G2_TILE(A2, B2, A1, B1, 0, 0, 0);          // tile 62, no stage, VMW0
  G2_TILE(A0, B0, A1, B1, 0, 0, 1);          // tile 63, last

  // epilogue: invs1 from S1p partials (L2-resident), then scaled NT store
  float iv[4];
#pragma unroll
  for (int nn = 0; nn < 4; ++nn) {
    int col = n0 + wn * 64 + nn * 16 + lane16;
    float ssum = 0.f;
#pragma unroll
    for (int j = 0; j < 16; ++j) ssum += S1p[j * 16384 + col];
    iv[nn] = 1.0f / ssum;
  }
  for (int m = 0; m < 4; ++m) {
    for (int r = 0; r < 4; ++r) {
      int crow = c0 + wm * 64 + m * 16 + kl * 4 + r;
      for (int nn = 0; nn < 4; ++nn) {
        int col = n0 + wn * 64 + nn * 16 + lane16;
        int bb = col >> 10, hw = col & 1023;
        __builtin_nontemporal_store(acc[m][nn][r] * iv[nn],
                                    &Q[bb * 524288 + crow * 1024 + hw]);
      }
    }
  }
}

extern "C" void kernel_launch(void* const* d_in, const int* in_sizes, int n_in,
                              void* d_out, int out_size, void* d_ws, size_t ws_size,
                              hipStream_t stream) {
  const float* feat = (const float*)d_in[0];   // (16, 512, 32, 32)
  const float* cb = (const float*)d_in[1];     // (4096, 512)
  float* out = (float*)d_out;
  float* q_out = out;                          // 8388608
  float* a_out = out + 8388608;                // 67108864
  float* d_dist = out + 75497472;              // 67108864

  char* ws = (char*)d_ws;
  u16* Xh = (u16*)(ws + 0);                    // 16 MB  fp16 X (n,c)
  u16* Eh = (u16*)(ws + 16777216);             // 4 MB   fp16 E (k,c)
  u16* Et = (u16*)(ws + 20971520);             // 4 MB   bf16 E^T (c,k) pi-order
  float* xnorm = (float*)(ws + 25165824);      // 64 KB
  float* enorm = (float*)(ws + 25231360);      // 16 KB
  float* S1p = (float*)(ws + 25247744);        // 1 MB  [16][16384]
  float* STp = (float*)(ws + 26296320);        // 1 MB
  u16* Pu = (u16*)(ws + 27410432);             // 128 MB -> ends ~155 MB

  prep_all<<<320, 256, 0, stream>>>(feat, cb, Xh, xnorm, Eh, enorm, Et);
  gemm1_8ph<<<1024, 512, 0, stream>>>(Xh, Eh, xnorm, enorm, d_dist, S1p, STp, Pu);
  softmax_out<<<256, 512, 0, stream>>>(d_dist, xnorm, STp, a_out);   // D L3-warm
  gemm2_3d<<<256, 512, 0, stream>>>(Et, Pu, S1p, q_out);
}

// Round 16
// 324.708 us; speedup vs baseline: 1.1660x; 1.0191x over previous
//
#include <hip/hip_runtime.h>
#include <hip/hip_bf16.h>
#include <stdint.h>

typedef unsigned short u16;
typedef _Float16 f16;
typedef f16 f16x8 __attribute__((ext_vector_type(8)));
typedef __bf16 bf16x8 __attribute__((ext_vector_type(8)));
typedef float f32x4 __attribute__((ext_vector_type(4)));
typedef uint32_t u32x2 __attribute__((ext_vector_type(2)));

#define INVT 14.2857142857142857f  // 1/0.07
#define CSH  32.0f                 // extra shift on T-path exponents (softmax-invariant)

__device__ __forceinline__ u16 f2b(float f) {
  __hip_bfloat16 h = __float2bfloat16(f);
  return __builtin_bit_cast(u16, h);
}
__device__ __forceinline__ u16 f2h(float f) {
  f16 h = (f16)f;
  return __builtin_bit_cast(u16, h);
}
__device__ __forceinline__ void g2l16(const void* g, void* l) {
  __builtin_amdgcn_global_load_lds(
      (__attribute__((address_space(1))) void*)(uintptr_t)g,
      (__attribute__((address_space(3))) void*)(uint32_t)(uintptr_t)l, 16, 0, 0);
}

// ---- merged prep: blocks 0..255 do feat->Xh/xnorm; 256..319 do cb->Eh/enorm/Et
// Et stored with per-64-chunk column permutation pi (position 4l+nf = k 16nf+l);
// gemm1 writes Pu in the same pi order, so pi cancels in gemm2's contraction.
__global__ __launch_bounds__(256) void prep_all(const float* __restrict__ feat,
    const float* __restrict__ cb, u16* __restrict__ Xh, float* __restrict__ xnorm,
    u16* __restrict__ Eh, float* __restrict__ enorm, u16* __restrict__ Et) {
  __shared__ __align__(16) char smraw[16640];
  int t = threadIdx.x;
  if (blockIdx.x < 256) {
    float (*sm)[65] = (float(*)[65])smraw;
    int b = blockIdx.x >> 4;
    int hw0 = (blockIdx.x & 15) << 6;
    int hwi = t & 63, ci0 = t >> 6;
    float xs2[2] = {0.f, 0.f};
    int cj = t & 7;
    for (int c0 = 0; c0 < 512; c0 += 64) {
      for (int ci = ci0; ci < 64; ci += 4)
        sm[ci][hwi] = feat[((b * 512 + c0 + ci) << 10) + hw0 + hwi];
      __syncthreads();
      for (int w = 0; w < 2; ++w) {
        int hj = (t >> 3) + (w << 5);
        int n = (b << 10) + hw0 + hj;
        uint32_t hp[4];
        for (int p = 0; p < 4; ++p) {
          float v0 = sm[cj * 8 + p * 2 + 0][hj];
          float v1 = sm[cj * 8 + p * 2 + 1][hj];
          xs2[w] += v0 * v0 + v1 * v1;
          hp[p] = (uint32_t)f2h(v0) | ((uint32_t)f2h(v1) << 16);
        }
        *(uint4*)(Xh + n * 512 + c0 + cj * 8) = make_uint4(hp[0], hp[1], hp[2], hp[3]);
      }
      __syncthreads();
    }
    for (int w = 0; w < 2; ++w) {
      float v = xs2[w];
      v += __shfl_xor(v, 1); v += __shfl_xor(v, 2); v += __shfl_xor(v, 4);
      if (cj == 0) {
        int hj = (t >> 3) + (w << 5);
        xnorm[(b << 10) + hw0 + hj] = v;
      }
    }
  } else {
    u16 (*sm)[72] = (u16(*)[72])smraw;
    int k0 = (blockIdx.x - 256) << 6;
    int kr = t >> 2, q = t & 3;
    float nrm = 0.f;
    for (int c0 = 0; c0 < 512; c0 += 64) {
      const float4* src = (const float4*)(cb + (size_t)(k0 + kr) * 512 + c0 + q * 16);
      float4 v[4];
      uint32_t hw_[8], bw[8];
#pragma unroll
      for (int p = 0; p < 4; ++p) {
        v[p] = src[p];
        nrm += v[p].x * v[p].x + v[p].y * v[p].y + v[p].z * v[p].z + v[p].w * v[p].w;
        hw_[p * 2 + 0] = (uint32_t)f2h(v[p].x) | ((uint32_t)f2h(v[p].y) << 16);
        hw_[p * 2 + 1] = (uint32_t)f2h(v[p].z) | ((uint32_t)f2h(v[p].w) << 16);
        bw[p * 2 + 0] = (uint32_t)f2b(v[p].x) | ((uint32_t)f2b(v[p].y) << 16);
        bw[p * 2 + 1] = (uint32_t)f2b(v[p].z) | ((uint32_t)f2b(v[p].w) << 16);
      }
      uint4* dstE = (uint4*)(Eh + (size_t)(k0 + kr) * 512 + c0 + q * 16);
      dstE[0] = make_uint4(hw_[0], hw_[1], hw_[2], hw_[3]);
      dstE[1] = make_uint4(hw_[4], hw_[5], hw_[6], hw_[7]);
      uint4* dstS = (uint4*)&sm[kr][q * 16];
      dstS[0] = make_uint4(bw[0], bw[1], bw[2], bw[3]);
      dstS[1] = make_uint4(bw[4], bw[5], bw[6], bw[7]);
      __syncthreads();
      int ci = t >> 2;
      uint32_t o[8];
#pragma unroll
      for (int j = 0; j < 8; ++j) {
        int jj0 = 2 * j, jj1 = 2 * j + 1;
        u16 a0 = sm[16 * (jj0 & 3) + q * 4 + (jj0 >> 2)][ci];
        u16 a1 = sm[16 * (jj1 & 3) + q * 4 + (jj1 >> 2)][ci];
        o[j] = (uint32_t)a0 | ((uint32_t)a1 << 16);
      }
      uint4* dstT = (uint4*)(Et + (size_t)(c0 + ci) * 4096 + k0 + q * 16);
      dstT[0] = make_uint4(o[0], o[1], o[2], o[3]);
      dstT[1] = make_uint4(o[4], o[5], o[6], o[7]);
      __syncthreads();
    }
    nrm += __shfl_xor(nrm, 1); nrm += __shfl_xor(nrm, 2);
    if (q == 0) enorm[k0 + kr] = nrm;
  }
}

// ============ GEMM1 (fp16): 256x256 tile, BK=64, 8 waves, 8-phase =============
__device__ __forceinline__ void stageA_g1(const u16* __restrict__ g, u16* l, int h, int t) {
  int r0 = t >> 3, c = ((t & 7) ^ (r0 & 7)) * 8, cw = (t & 7) * 8;
  int ra = h * 64 + r0, rb = 128 + h * 64 + r0;
  g2l16(g + ra * 512 + c, l + ra * 64 + cw);
  g2l16(g + rb * 512 + c, l + rb * 64 + cw);
}
__device__ __forceinline__ void stageB_g1(const u16* __restrict__ g, u16* l, int hb, int t) {
  int r0 = t >> 3, c = ((t & 7) ^ (r0 & 7)) * 8, cw = (t & 7) * 8;
  int ra = (r0 >> 5) * 64 + hb * 32 + (r0 & 31);
  int rb = ((r0 + 64) >> 5) * 64 + hb * 32 + (r0 & 31);
  g2l16(g + ra * 512 + c, l + ra * 64 + cw);
  g2l16(g + rb * 512 + c, l + rb * 64 + cw);
}

template<int Q>
__device__ __forceinline__ void phase_ld(const u16* Ab, const u16* Bb,
    int wm, int wn, int lane16, int kl, f16x8 (&af)[4][2], f16x8 (&bf2)[2][2]) {
  int sw = lane16 & 7;
  if constexpr (Q == 0 || Q == 2) {
#pragma unroll
    for (int m = 0; m < 4; ++m)
#pragma unroll
      for (int s = 0; s < 2; ++s)
        af[m][s] = *(const f16x8*)(Ab + (wm * 128 + ((Q >> 1) * 4 + m) * 16 + lane16) * 64
                                   + (((s * 4 + kl) ^ sw) * 8));
  }
  if constexpr (Q != 2) {
    constexpr int NF0 = (Q == 1) ? 2 : 0;
#pragma unroll
    for (int n = 0; n < 2; ++n)
#pragma unroll
      for (int s = 0; s < 2; ++s)
        bf2[n][s] = *(const f16x8*)(Bb + (wn * 64 + (NF0 + n) * 16 + lane16) * 64
                                    + (((s * 4 + kl) ^ sw) * 8));
  }
}
template<int Q>
__device__ __forceinline__ void phase_mm(f16x8 (&af)[4][2], f16x8 (&bf2)[2][2],
                                         f32x4 (&acc)[8][4]) {
  constexpr int MQ = (Q >> 1) * 4;
  constexpr int NF0 = (Q == 1 || Q == 2) ? 2 : 0;
#pragma unroll
  for (int m = 0; m < 4; ++m)
#pragma unroll
    for (int n = 0; n < 2; ++n)
#pragma unroll
      for (int s = 0; s < 2; ++s)
        acc[MQ + m][NF0 + n] = __builtin_amdgcn_mfma_f32_16x16x32_f16(
            af[m][s], bf2[n][s], acc[MQ + m][NF0 + n], 0, 0, 0);
}

#define FENCE() asm volatile("" ::: "memory")
#define BAR() __builtin_amdgcn_s_barrier()
#define VMW6() asm volatile("s_waitcnt vmcnt(6)" ::: "memory")
#define VMW4() asm volatile("s_waitcnt vmcnt(4)" ::: "memory")
#define VMW0() asm volatile("s_waitcnt vmcnt(0)" ::: "memory")

__global__ __launch_bounds__(512, 2) void gemm1_8ph(const u16* __restrict__ Xh,
    const u16* __restrict__ Eh, const float* __restrict__ xnorm,
    const float* __restrict__ enorm, float* __restrict__ D,
    float* __restrict__ S1p, float* __restrict__ STp, u16* __restrict__ Pu) {
  __shared__ __align__(16) u16 lds[2][2][256 * 64];  // 128 KB
  int bid = blockIdx.x;
  int s = (bid & 7) * 128 + (bid >> 3);   // XCD swizzle, bijective (1024 % 8 == 0)
  int rt = s >> 4, ct = s & 15;
  int n0 = rt << 8, k0 = ct << 8;
  int t = threadIdx.x;
  int l = t & 63, w = t >> 6;
  int wm = w >> 2, wn = w & 3;
  int lane16 = l & 15, kl = l >> 4;

  u16* lA0 = &lds[0][0][0]; u16* lB0 = &lds[0][1][0];
  u16* lA1 = &lds[1][0][0]; u16* lB1 = &lds[1][1][0];

  auto gA = [&](int kt) { return Xh + n0 * 512 + kt * 64; };
  auto gB = [&](int kt) { return Eh + k0 * 512 + kt * 64; };

  f32x4 acc[8][4];
#pragma unroll
  for (int m = 0; m < 8; ++m)
#pragma unroll
    for (int n = 0; n < 4; ++n) acc[m][n] = f32x4{0.f, 0.f, 0.f, 0.f};
  f16x8 af[4][2], bf2[2][2];

  stageA_g1(gA(0), lA0, 0, t);
  stageB_g1(gB(0), lB0, 1, t);
  stageB_g1(gB(0), lB0, 0, t);
  stageA_g1(gA(0), lA0, 1, t);
  stageA_g1(gA(1), lA1, 0, t);
  stageB_g1(gB(1), lB1, 1, t);
  VMW4();
  BAR();

#pragma unroll 1
  for (int i = 0; i < 4; ++i) {
    int ktO = 2 * i + 1;
    int ktE2 = 2 * i + 2, ktO2 = 2 * i + 3;
    bool more = (i < 3);
    phase_ld<0>(lA0, lB0, wm, wn, lane16, kl, af, bf2);
    stageB_g1(gB(ktO), lB1, 0, t);
    FENCE(); BAR();
    __builtin_amdgcn_s_setprio(1); phase_mm<0>(af, bf2, acc); __builtin_amdgcn_s_setprio(0);
    FENCE(); BAR();
    phase_ld<1>(lA0, lB0, wm, wn, lane16, kl, af, bf2);
    stageA_g1(gA(ktO), lA1, 1, t);
    FENCE(); BAR();
    __builtin_amdgcn_s_setprio(1); phase_mm<1>(af, bf2, acc); __builtin_amdgcn_s_setprio(0);
    FENCE(); BAR();
    phase_ld<2>(lA0, lB0, wm, wn, lane16, kl, af, bf2);
    if (more) stageA_g1(gA(ktE2), lA0, 0, t);
    FENCE(); BAR();
    __builtin_amdgcn_s_setprio(1); phase_mm<2>(af, bf2, acc); __builtin_amdgcn_s_setprio(0);
    FENCE(); BAR();
    phase_ld<3>(lA0, lB0, wm, wn, lane16, kl, af, bf2);
    if (more) stageB_g1(gB(ktE2), lB0, 1, t);
    FENCE(); BAR();
    __builtin_amdgcn_s_setprio(1); phase_mm<3>(af, bf2, acc); __builtin_amdgcn_s_setprio(0);
    if (i == 3) { VMW0(); } else { VMW4(); }
    BAR();
    phase_ld<0>(lA1, lB1, wm, wn, lane16, kl, af, bf2);
    if (more) stageB_g1(gB(ktE2), lB0, 0, t);
    FENCE(); BAR();
    __builtin_amdgcn_s_setprio(1); phase_mm<0>(af, bf2, acc); __builtin_amdgcn_s_setprio(0);
    FENCE(); BAR();
    phase_ld<1>(lA1, lB1, wm, wn, lane16, kl, af, bf2);
    if (more) stageA_g1(gA(ktE2), lA0, 1, t);
    FENCE(); BAR();
    __builtin_amdgcn_s_setprio(1); phase_mm<1>(af, bf2, acc); __builtin_amdgcn_s_setprio(0);
    FENCE(); BAR();
    phase_ld<2>(lA1, lB1, wm, wn, lane16, kl, af, bf2);
    if (more) stageA_g1(gA(ktO2), lA1, 0, t);
    FENCE(); BAR();
    __builtin_amdgcn_s_setprio(1); phase_mm<2>(af, bf2, acc); __builtin_amdgcn_s_setprio(0);
    FENCE(); BAR();
    phase_ld<3>(lA1, lB1, wm, wn, lane16, kl, af, bf2);
    if (more) stageB_g1(gB(ktO2), lB1, 1, t);
    FENCE(); BAR();
    __builtin_amdgcn_s_setprio(1); phase_mm<3>(af, bf2, acc); __builtin_amdgcn_s_setprio(0);
    if (more) { VMW4(); }
    BAR();
  }

  // epilogue: D = xnorm - l (cached; softmax reads next); Pu = bf16(exp(l)) NT
  float en[4];
#pragma unroll
  for (int nf = 0; nf < 4; ++nf) en[nf] = enorm[k0 + wn * 64 + nf * 16 + lane16];
  float* ldsS = (float*)&lds[0][0][0];   // [256][4]
  float* ldsT = ldsS + 1024;             // [256][4]
#pragma unroll
  for (int mf = 0; mf < 8; ++mf) {
#pragma unroll
    for (int r = 0; r < 4; ++r) {
      int lrow = wm * 128 + mf * 16 + kl * 4 + r;
      int row = n0 + lrow;
      float xv = xnorm[row];
      float lv[4], ev[4];
#pragma unroll
      for (int nf = 0; nf < 4; ++nf) lv[nf] = 2.0f * acc[mf][nf][r] - en[nf];
      float* Drow = D + (size_t)row * 4096 + k0 + wn * 64 + lane16;
#pragma unroll
      for (int nf = 0; nf < 4; ++nf) Drow[nf * 16] = xv - lv[nf];
#pragma unroll
      for (int nf = 0; nf < 4; ++nf) ev[nf] = __expf(lv[nf]);
      u32x2 pp;
      pp[0] = (uint32_t)f2b(ev[0]) | ((uint32_t)f2b(ev[1]) << 16);
      pp[1] = (uint32_t)f2b(ev[2]) | ((uint32_t)f2b(ev[3]) << 16);
      __builtin_nontemporal_store(pp,
          (u32x2*)(Pu + (size_t)row * 4096 + k0 + wn * 64 + lane16 * 4));
      float s1 = ev[0] + ev[1] + ev[2] + ev[3];
      float sT = __expf(lv[0] * INVT - CSH) + __expf(lv[1] * INVT - CSH)
               + __expf(lv[2] * INVT - CSH) + __expf(lv[3] * INVT - CSH);
#pragma unroll
      for (int o = 1; o < 16; o <<= 1) { s1 += __shfl_xor(s1, o); sT += __shfl_xor(sT, o); }
      if (lane16 == 0) { ldsS[lrow * 4 + wn] = s1; ldsT[lrow * 4 + wn] = sT; }
    }
  }
  __syncthreads();
  {
    int rr = t & 255;
    if (t < 256) {
      float v = ldsS[rr * 4 + 0] + ldsS[rr * 4 + 1] + ldsS[rr * 4 + 2] + ldsS[rr * 4 + 3];
      S1p[ct * 16384 + n0 + rr] = v;
    } else {
      float v = ldsT[rr * 4 + 0] + ldsT[rr * 4 + 1] + ldsT[rr * 4 + 2] + ldsT[rr * 4 + 3];
      STp[ct * 16384 + n0 + rr] = v;
    }
  }
}

// ========== fused tail: per-block sequential {softmax tile -> gemm2 tile} =====
// gemm2's tile-0 loads are issued at entry into buf0; their HBM latency hides
// under the whole softmax phase. tt overlays buf1/buf2 (freed by barrier).
__device__ __forceinline__ void stageA2(const u16* __restrict__ g, u16* l, int h, int t) {
  int ri = t >> 3, ch = t & 7;
  int r = (ri >> 5) * 64 + h * 32 + (ri & 31);
  g2l16(g + (size_t)r * 4096 + ((ch ^ (r & 7)) * 8), l + r * 64 + ch * 8);
}
__device__ __forceinline__ void stageB2(const u16* __restrict__ g, u16* l, int h, int j, int t) {
  int ri = j * 64 + (t >> 3), ch = t & 7;
  int r = (ri >> 5) * 64 + h * 32 + (ri & 31);
  g2l16(g + (size_t)r * 4096 + ((ch ^ (r & 7)) * 8), l + r * 64 + ch * 8);
}

template<int P>
__device__ __forceinline__ void phase_ldN(const u16* Ab, const u16* Bb,
    int wm, int wn, int lane16, int kl, bf16x8 (&af)[2][2], bf16x8 (&bf)[4][2]) {
  int sw = lane16 & 7;
#pragma unroll
  for (int m = 0; m < 2; ++m)
#pragma unroll
    for (int s = 0; s < 2; ++s)
      af[m][s] = *(const bf16x8*)(Ab + (wm * 64 + (P * 2 + m) * 16 + lane16) * 64
                                  + (((s * 4 + kl) ^ sw) * 8));
  if constexpr (P == 0) {
#pragma unroll
    for (int n = 0; n < 4; ++n)
#pragma unroll
      for (int s = 0; s < 2; ++s)
        bf[n][s] = *(const bf16x8*)(Bb + (wn * 64 + n * 16 + lane16) * 64
                                    + (((s * 4 + kl) ^ sw) * 8));
  }
}
template<int P>
__device__ __forceinline__ void phase_mmN(bf16x8 (&af)[2][2], bf16x8 (&bf)[4][2],
                                          f32x4 (&acc)[4][4]) {
#pragma unroll
  for (int m = 0; m < 2; ++m)
#pragma unroll
    for (int n = 0; n < 4; ++n)
#pragma unroll
      for (int s = 0; s < 2; ++s)
        acc[P * 2 + m][n] = __builtin_amdgcn_mfma_f32_16x16x32_bf16(
            af[m][s], bf[n][s], acc[P * 2 + m][n], 0, 0, 0);
}

#define G2_TILE(Ab, Bb, An, Bn, kn, ST, LASTW) \
  { const u16* gAn = gA + (kn) * 64; const u16* gBn = gB + (kn) * 64; \
    phase_ldN<0>(Ab, Bb, wm, wn, lane16, kl, af, bf); \
    if (ST) { stageA2(gAn, An, 0, t); stageA2(gAn, An, 1, t); } \
    FENCE(); BAR(); \
    __builtin_amdgcn_s_setprio(1); phase_mmN<0>(af, bf, acc); __builtin_amdgcn_s_setprio(0); \
    FENCE(); BAR(); \
    phase_ldN<1>(Ab, Bb, wm, wn, lane16, kl, af, bf); \
    if (ST) { stageB2(gBn, Bn, 0, 0, t); stageB2(gBn, Bn, 0, 1, t); \
              stageB2(gBn, Bn, 1, 0, t); stageB2(gBn, Bn, 1, 1, t); } \
    FENCE(); BAR(); \
    __builtin_amdgcn_s_setprio(1); phase_mmN<1>(af, bf, acc); __builtin_amdgcn_s_setprio(0); \
    if (!(LASTW)) { if (ST) { VMW6(); } else { VMW0(); } BAR(); } }

__global__ __launch_bounds__(512, 1) void fused_tail(const float* __restrict__ D,
    const float* __restrict__ xnorm, const float* __restrict__ STp,
    float* __restrict__ assign, const u16* __restrict__ Et,
    const u16* __restrict__ Pu, const float* __restrict__ S1p, float* __restrict__ Q) {
  __shared__ __align__(16) u16 lds3[3][384 * 64];  // 144 KB
  int bid = blockIdx.x;
  int t = threadIdx.x;

  // gemm2 tile coords (needed now for pre-staging)
  int s2 = (bid & 7) * 32 + (bid >> 3);
  int ct = s2 >> 2, rt2 = s2 & 3;
  int c0 = rt2 << 7, n0g = ct << 8;
  const u16* gA = Et + (size_t)c0 * 4096;
  const u16* gB = Pu + (size_t)n0g * 4096;
  u16* A0 = &lds3[0][0]; u16* B0 = &lds3[0][128 * 64];
  u16* A1 = &lds3[1][0]; u16* B1 = &lds3[1][128 * 64];
  u16* A2 = &lds3[2][0]; u16* B2 = &lds3[2][128 * 64];

  // pre-stage gemm2 tile 0 into buf0 (latency hides under softmax phase)
  stageA2(gA + 0 * 64, A0, 0, t); stageA2(gA + 0 * 64, A0, 1, t);
  stageB2(gB + 0 * 64, B0, 0, 0, t); stageB2(gB + 0 * 64, B0, 0, 1, t);
  stageB2(gB + 0 * 64, B0, 1, 0, t); stageB2(gB + 0 * 64, B0, 1, 1, t);

  // ---------------- phase 1: softmax tile (tt overlays buf1/buf2) -------------
  {
    float (*tt)[132] = (float(*)[132])&lds3[1][0];   // 67.6 KB within 96 KB
    int ng = bid >> 1, kh = bid & 1;
    int n0 = ng << 7;
    int b = n0 >> 10, hw0 = n0 & 1023;
    int i = t >> 2, jc = t & 3;
    int row = n0 + i;
    float sT = 0.f;
#pragma unroll
    for (int p = 0; p < 4; ++p) sT += STp[(jc * 4 + p) * 16384 + row];
    sT += __shfl_xor(sT, 1); sT += __shfl_xor(sT, 2);
    float isT = 1.0f / sT;
    float xn = xnorm[row];
    int kbase = kh << 11;
    const float* Dr = D + (size_t)row * 4096 + kbase;
    float* assignB = assign + (size_t)b * 4194304 + hw0;

    for (int kt = 0; kt < 16; ++kt) {
      int kb = kt << 7;
#pragma unroll
      for (int it = 0; it < 8; ++it) {
        int col4 = it * 16 + jc * 4;
        float4 dv = *(const float4*)(Dr + kb + col4);
        tt[col4 + 0][i] = __expf((xn - dv.x) * INVT - CSH) * isT;
        tt[col4 + 1][i] = __expf((xn - dv.y) * INVT - CSH) * isT;
        tt[col4 + 2][i] = __expf((xn - dv.z) * INVT - CSH) * isT;
        tt[col4 + 3][i] = __expf((xn - dv.w) * INVT - CSH) * isT;
      }
      __syncthreads();
#pragma unroll
      for (int p = 0; p < 8; ++p) {
        int idx = t + (p << 9);
        int j = idx >> 5, ic = idx & 31;
        f32x4 o;
        o[0] = tt[j][ic * 4 + 0]; o[1] = tt[j][ic * 4 + 1];
        o[2] = tt[j][ic * 4 + 2]; o[3] = tt[j][ic * 4 + 3];
        __builtin_nontemporal_store(o,
            (f32x4*)(assignB + (size_t)(kbase + kb + j) * 1024 + ic * 4));
      }
      __syncthreads();
    }
  }

  // ---------------- phase 2: gemm2 tile (3-deep, 2-phase/tile) ----------------
  int l = t & 63, w = t >> 6;
  int wm = w >> 2, wn = w & 3;
  int lane16 = l & 15, kl = l >> 4;

  f32x4 acc[4][4];
#pragma unroll
  for (int m = 0; m < 4; ++m)
#pragma unroll
    for (int n = 0; n < 4; ++n) acc[m][n] = f32x4{0.f, 0.f, 0.f, 0.f};
  bf16x8 af[2][2], bf[4][2];

  // stage tile 1 into buf1 (tt region freed by the loop's final __syncthreads)
  stageA2(gA + 1 * 64, A1, 0, t); stageA2(gA + 1 * 64, A1, 1, t);
  stageB2(gB + 1 * 64, B1, 0, 0, t); stageB2(gB + 1 * 64, B1, 0, 1, t);
  stageB2(gB + 1 * 64, B1, 1, 0, t); stageB2(gB + 1 * 64, B1, 1, 1, t);
  VMW6();   // drains everything older than tile-1's 6 loads (incl. tile 0)
  BAR();

#pragma unroll 1
  for (int j = 0; j < 20; ++j) {
    int kt = 3 * j;
    G2_TILE(A0, B0, A2, B2, kt + 2, 1, 0);
    G2_TILE(A1, B1, A0, B0, kt + 3, 1, 0);
    G2_TILE(A2, B2, A1, B1, kt + 4, 1, 0);
  }
  G2_TILE(A0, B0, A2, B2, 62, 1, 0);
  G2_TILE(A1, B1, A0, B0, 63, 1, 0);
  G2_TILE(A2, B2, A1, B1, 0, 0, 0);
  G2_TILE(A0, B0, A1, B1, 0, 0, 1);

  float iv[4];
#pragma unroll
  for (int nn = 0; nn < 4; ++nn) {
    int col = n0g + wn * 64 + nn * 16 + lane16;
    float ssum = 0.f;
#pragma unroll
    for (int j = 0; j < 16; ++j) ssum += S1p[j * 16384 + col];
    iv[nn] = 1.0f / ssum;
  }
  for (int m = 0; m < 4; ++m) {
    for (int r = 0; r < 4; ++r) {
      int crow = c0 + wm * 64 + m * 16 + kl * 4 + r;
      for (int nn = 0; nn < 4; ++nn) {
        int col = n0g + wn * 64 + nn * 16 + lane16;
        int bb = col >> 10, hw = col & 1023;
        __builtin_nontemporal_store(acc[m][nn][r] * iv[nn],
                                    &Q[bb * 524288 + crow * 1024 + hw]);
      }
    }
  }
}

extern "C" void kernel_launch(void* const* d_in, const int* in_sizes, int n_in,
                              void* d_out, int out_size, void* d_ws, size_t ws_size,
                              hipStream_t stream) {
  const float* feat = (const float*)d_in[0];   // (16, 512, 32, 32)
  const float* cb = (const float*)d_in[1];     // (4096, 512)
  float* out = (float*)d_out;
  float* q_out = out;                          // 8388608
  float* a_out = out + 8388608;                // 67108864
  float* d_dist = out + 75497472;              // 67108864

  char* ws = (char*)d_ws;
  u16* Xh = (u16*)(ws + 0);                    // 16 MB  fp16 X (n,c)
  u16* Eh = (u16*)(ws + 16777216);             // 4 MB   fp16 E (k,c)
  u16* Et = (u16*)(ws + 20971520);             // 4 MB   bf16 E^T (c,k) pi-order
  float* xnorm = (float*)(ws + 25165824);      // 64 KB
  float* enorm = (float*)(ws + 25231360);      // 16 KB
  float* S1p = (float*)(ws + 25247744);        // 1 MB  [16][16384]
  float* STp = (float*)(ws + 26296320);        // 1 MB
  u16* Pu = (u16*)(ws + 27410432);             // 128 MB -> ends ~155 MB

  prep_all<<<320, 256, 0, stream>>>(feat, cb, Xh, xnorm, Eh, enorm, Et);
  gemm1_8ph<<<1024, 512, 0, stream>>>(Xh, Eh, xnorm, enorm, d_dist, S1p, STp, Pu);
  fused_tail<<<256, 512, 0, stream>>>(d_dist, xnorm, STp, a_out, Et, Pu, S1p, q_out);
}

// Round 17
// 321.838 us; speedup vs baseline: 1.1764x; 1.0089x over previous
//
#include <hip/hip_runtime.h>
#include <hip/hip_bf16.h>
#include <stdint.h>

typedef unsigned short u16;
typedef _Float16 f16;
typedef f16 f16x8 __attribute__((ext_vector_type(8)));
typedef __bf16 bf16x8 __attribute__((ext_vector_type(8)));
typedef float f32x4 __attribute__((ext_vector_type(4)));
typedef uint32_t u32x2 __attribute__((ext_vector_type(2)));

#define INVT 14.2857142857142857f  // 1/0.07
#define CSH  32.0f                 // extra shift on T-path exponents (softmax-invariant)

__device__ __forceinline__ u16 f2b(float f) {
  __hip_bfloat16 h = __float2bfloat16(f);
  return __builtin_bit_cast(u16, h);
}
__device__ __forceinline__ u16 f2h(float f) {
  f16 h = (f16)f;
  return __builtin_bit_cast(u16, h);
}
__device__ __forceinline__ void g2l16(const void* g, void* l) {
  __builtin_amdgcn_global_load_lds(
      (__attribute__((address_space(1))) void*)(uintptr_t)g,
      (__attribute__((address_space(3))) void*)(uint32_t)(uintptr_t)l, 16, 0, 0);
}

// ---- merged prep: blocks 0..255 do feat->Xh/xnorm; 256..319 do cb->Eh/enorm/Et
// Et stored with per-64-chunk column permutation pi (position 4l+nf = k 16nf+l);
// gemm1 writes Pu in the same pi order, so pi cancels in gemm2's contraction.
__global__ __launch_bounds__(256) void prep_all(const float* __restrict__ feat,
    const float* __restrict__ cb, u16* __restrict__ Xh, float* __restrict__ xnorm,
    u16* __restrict__ Eh, float* __restrict__ enorm, u16* __restrict__ Et) {
  __shared__ __align__(16) char smraw[16640];
  int t = threadIdx.x;
  if (blockIdx.x < 256) {
    float (*sm)[65] = (float(*)[65])smraw;
    int b = blockIdx.x >> 4;
    int hw0 = (blockIdx.x & 15) << 6;
    int hwi = t & 63, ci0 = t >> 6;
    float xs2[2] = {0.f, 0.f};
    int cj = t & 7;
    for (int c0 = 0; c0 < 512; c0 += 64) {
      for (int ci = ci0; ci < 64; ci += 4)
        sm[ci][hwi] = feat[((b * 512 + c0 + ci) << 10) + hw0 + hwi];
      __syncthreads();
      for (int w = 0; w < 2; ++w) {
        int hj = (t >> 3) + (w << 5);
        int n = (b << 10) + hw0 + hj;
        uint32_t hp[4];
        for (int p = 0; p < 4; ++p) {
          float v0 = sm[cj * 8 + p * 2 + 0][hj];
          float v1 = sm[cj * 8 + p * 2 + 1][hj];
          xs2[w] += v0 * v0 + v1 * v1;
          hp[p] = (uint32_t)f2h(v0) | ((uint32_t)f2h(v1) << 16);
        }
        *(uint4*)(Xh + n * 512 + c0 + cj * 8) = make_uint4(hp[0], hp[1], hp[2], hp[3]);
      }
      __syncthreads();
    }
    for (int w = 0; w < 2; ++w) {
      float v = xs2[w];
      v += __shfl_xor(v, 1); v += __shfl_xor(v, 2); v += __shfl_xor(v, 4);
      if (cj == 0) {
        int hj = (t >> 3) + (w << 5);
        xnorm[(b << 10) + hw0 + hj] = v;
      }
    }
  } else {
    u16 (*sm)[72] = (u16(*)[72])smraw;
    int k0 = (blockIdx.x - 256) << 6;
    int kr = t >> 2, q = t & 3;
    float nrm = 0.f;
    for (int c0 = 0; c0 < 512; c0 += 64) {
      const float4* src = (const float4*)(cb + (size_t)(k0 + kr) * 512 + c0 + q * 16);
      float4 v[4];
      uint32_t hw_[8], bw[8];
#pragma unroll
      for (int p = 0; p < 4; ++p) {
        v[p] = src[p];
        nrm += v[p].x * v[p].x + v[p].y * v[p].y + v[p].z * v[p].z + v[p].w * v[p].w;
        hw_[p * 2 + 0] = (uint32_t)f2h(v[p].x) | ((uint32_t)f2h(v[p].y) << 16);
        hw_[p * 2 + 1] = (uint32_t)f2h(v[p].z) | ((uint32_t)f2h(v[p].w) << 16);
        bw[p * 2 + 0] = (uint32_t)f2b(v[p].x) | ((uint32_t)f2b(v[p].y) << 16);
        bw[p * 2 + 1] = (uint32_t)f2b(v[p].z) | ((uint32_t)f2b(v[p].w) << 16);
      }
      uint4* dstE = (uint4*)(Eh + (size_t)(k0 + kr) * 512 + c0 + q * 16);
      dstE[0] = make_uint4(hw_[0], hw_[1], hw_[2], hw_[3]);
      dstE[1] = make_uint4(hw_[4], hw_[5], hw_[6], hw_[7]);
      uint4* dstS = (uint4*)&sm[kr][q * 16];
      dstS[0] = make_uint4(bw[0], bw[1], bw[2], bw[3]);
      dstS[1] = make_uint4(bw[4], bw[5], bw[6], bw[7]);
      __syncthreads();
      int ci = t >> 2;
      uint32_t o[8];
#pragma unroll
      for (int j = 0; j < 8; ++j) {
        int jj0 = 2 * j, jj1 = 2 * j + 1;
        u16 a0 = sm[16 * (jj0 & 3) + q * 4 + (jj0 >> 2)][ci];
        u16 a1 = sm[16 * (jj1 & 3) + q * 4 + (jj1 >> 2)][ci];
        o[j] = (uint32_t)a0 | ((uint32_t)a1 << 16);
      }
      uint4* dstT = (uint4*)(Et + (size_t)(c0 + ci) * 4096 + k0 + q * 16);
      dstT[0] = make_uint4(o[0], o[1], o[2], o[3]);
      dstT[1] = make_uint4(o[4], o[5], o[6], o[7]);
      __syncthreads();
    }
    nrm += __shfl_xor(nrm, 1); nrm += __shfl_xor(nrm, 2);
    if (q == 0) enorm[k0 + kr] = nrm;
  }
}

// ============ GEMM1 (fp16): 256x256 tile, BK=64, 8 waves, 8-phase =============
__device__ __forceinline__ void stageA_g1(const u16* __restrict__ g, u16* l, int h, int t) {
  int r0 = t >> 3, c = ((t & 7) ^ (r0 & 7)) * 8, cw = (t & 7) * 8;
  int ra = h * 64 + r0, rb = 128 + h * 64 + r0;
  g2l16(g + ra * 512 + c, l + ra * 64 + cw);
  g2l16(g + rb * 512 + c, l + rb * 64 + cw);
}
__device__ __forceinline__ void stageB_g1(const u16* __restrict__ g, u16* l, int hb, int t) {
  int r0 = t >> 3, c = ((t & 7) ^ (r0 & 7)) * 8, cw = (t & 7) * 8;
  int ra = (r0 >> 5) * 64 + hb * 32 + (r0 & 31);
  int rb = ((r0 + 64) >> 5) * 64 + hb * 32 + (r0 & 31);
  g2l16(g + ra * 512 + c, l + ra * 64 + cw);
  g2l16(g + rb * 512 + c, l + rb * 64 + cw);
}

template<int Q>
__device__ __forceinline__ void phase_ld(const u16* Ab, const u16* Bb,
    int wm, int wn, int lane16, int kl, f16x8 (&af)[4][2], f16x8 (&bf2)[2][2]) {
  int sw = lane16 & 7;
  if constexpr (Q == 0 || Q == 2) {
#pragma unroll
    for (int m = 0; m < 4; ++m)
#pragma unroll
      for (int s = 0; s < 2; ++s)
        af[m][s] = *(const f16x8*)(Ab + (wm * 128 + ((Q >> 1) * 4 + m) * 16 + lane16) * 64
                                   + (((s * 4 + kl) ^ sw) * 8));
  }
  if constexpr (Q != 2) {
    constexpr int NF0 = (Q == 1) ? 2 : 0;
#pragma unroll
    for (int n = 0; n < 2; ++n)
#pragma unroll
      for (int s = 0; s < 2; ++s)
        bf2[n][s] = *(const f16x8*)(Bb + (wn * 64 + (NF0 + n) * 16 + lane16) * 64
                                    + (((s * 4 + kl) ^ sw) * 8));
  }
}
template<int Q>
__device__ __forceinline__ void phase_mm(f16x8 (&af)[4][2], f16x8 (&bf2)[2][2],
                                         f32x4 (&acc)[8][4]) {
  constexpr int MQ = (Q >> 1) * 4;
  constexpr int NF0 = (Q == 1 || Q == 2) ? 2 : 0;
#pragma unroll
  for (int m = 0; m < 4; ++m)
#pragma unroll
    for (int n = 0; n < 2; ++n)
#pragma unroll
      for (int s = 0; s < 2; ++s)
        acc[MQ + m][NF0 + n] = __builtin_amdgcn_mfma_f32_16x16x32_f16(
            af[m][s], bf2[n][s], acc[MQ + m][NF0 + n], 0, 0, 0);
}

#define FENCE() asm volatile("" ::: "memory")
#define BAR() __builtin_amdgcn_s_barrier()
#define VMW6() asm volatile("s_waitcnt vmcnt(6)" ::: "memory")
#define VMW4() asm volatile("s_waitcnt vmcnt(4)" ::: "memory")
#define VMW0() asm volatile("s_waitcnt vmcnt(0)" ::: "memory")

// epilogue half: rows [MF0*16, MF0*16+64) of this wave's tile (mf MF0..MF0+3)
#define EPI_HALF(MF0) \
  _Pragma("unroll") \
  for (int mf = (MF0); mf < (MF0) + 4; ++mf) { \
    _Pragma("unroll") \
    for (int r = 0; r < 4; ++r) { \
      int lrow = wm * 128 + mf * 16 + kl * 4 + r; \
      int row = n0 + lrow; \
      float xv = xnorm[row]; \
      float lv[4], ev[4]; \
      _Pragma("unroll") \
      for (int nf = 0; nf < 4; ++nf) lv[nf] = 2.0f * acc[mf][nf][r] - en[nf]; \
      float* Drow = D + (size_t)row * 4096 + k0 + wn * 64 + lane16; \
      _Pragma("unroll") \
      for (int nf = 0; nf < 4; ++nf) Drow[nf * 16] = xv - lv[nf]; \
      _Pragma("unroll") \
      for (int nf = 0; nf < 4; ++nf) ev[nf] = __expf(lv[nf]); \
      u32x2 pp; \
      pp[0] = (uint32_t)f2b(ev[0]) | ((uint32_t)f2b(ev[1]) << 16); \
      pp[1] = (uint32_t)f2b(ev[2]) | ((uint32_t)f2b(ev[3]) << 16); \
      __builtin_nontemporal_store(pp, \
          (u32x2*)(Pu + (size_t)row * 4096 + k0 + wn * 64 + lane16 * 4)); \
      float s1 = ev[0] + ev[1] + ev[2] + ev[3]; \
      float sT = __expf(lv[0] * INVT - CSH) + __expf(lv[1] * INVT - CSH) \
               + __expf(lv[2] * INVT - CSH) + __expf(lv[3] * INVT - CSH); \
      _Pragma("unroll") \
      for (int o = 1; o < 16; o <<= 1) { s1 += __shfl_xor(s1, o); sT += __shfl_xor(sT, o); } \
      if (lane16 == 0) { ldsS[lrow * 4 + wn] = s1; ldsT[lrow * 4 + wn] = sT; } \
    } \
  }

__global__ __launch_bounds__(512, 2) void gemm1_8ph(const u16* __restrict__ Xh,
    const u16* __restrict__ Eh, const float* __restrict__ xnorm,
    const float* __restrict__ enorm, float* __restrict__ D,
    float* __restrict__ S1p, float* __restrict__ STp, u16* __restrict__ Pu) {
  __shared__ __align__(16) u16 lds[2][2][256 * 64];  // 128 KB
  int bid = blockIdx.x;
  int s = (bid & 7) * 128 + (bid >> 3);   // XCD swizzle, bijective (1024 % 8 == 0)
  int rt = s >> 4, ct = s & 15;
  int n0 = rt << 8, k0 = ct << 8;
  int t = threadIdx.x;
  int l = t & 63, w = t >> 6;
  int wm = w >> 2, wn = w & 3;
  int lane16 = l & 15, kl = l >> 4;

  u16* lA0 = &lds[0][0][0]; u16* lB0 = &lds[0][1][0];
  u16* lA1 = &lds[1][0][0]; u16* lB1 = &lds[1][1][0];

  auto gA = [&](int kt) { return Xh + n0 * 512 + kt * 64; };
  auto gB = [&](int kt) { return Eh + k0 * 512 + kt * 64; };

  f32x4 acc[8][4];
#pragma unroll
  for (int m = 0; m < 8; ++m)
#pragma unroll
    for (int n = 0; n < 4; ++n) acc[m][n] = f32x4{0.f, 0.f, 0.f, 0.f};
  f16x8 af[4][2], bf2[2][2];

  stageA_g1(gA(0), lA0, 0, t);
  stageB_g1(gB(0), lB0, 1, t);
  stageB_g1(gB(0), lB0, 0, t);
  stageA_g1(gA(0), lA0, 1, t);
  stageA_g1(gA(1), lA1, 0, t);
  stageB_g1(gB(1), lB1, 1, t);
  VMW4();
  BAR();

#pragma unroll 1
  for (int i = 0; i < 3; ++i) {
    int ktO = 2 * i + 1;
    int ktE2 = 2 * i + 2, ktO2 = 2 * i + 3;
    phase_ld<0>(lA0, lB0, wm, wn, lane16, kl, af, bf2);
    stageB_g1(gB(ktO), lB1, 0, t);
    FENCE(); BAR();
    __builtin_amdgcn_s_setprio(1); phase_mm<0>(af, bf2, acc); __builtin_amdgcn_s_setprio(0);
    FENCE(); BAR();
    phase_ld<1>(lA0, lB0, wm, wn, lane16, kl, af, bf2);
    stageA_g1(gA(ktO), lA1, 1, t);
    FENCE(); BAR();
    __builtin_amdgcn_s_setprio(1); phase_mm<1>(af, bf2, acc); __builtin_amdgcn_s_setprio(0);
    FENCE(); BAR();
    phase_ld<2>(lA0, lB0, wm, wn, lane16, kl, af, bf2);
    stageA_g1(gA(ktE2), lA0, 0, t);
    FENCE(); BAR();
    __builtin_amdgcn_s_setprio(1); phase_mm<2>(af, bf2, acc); __builtin_amdgcn_s_setprio(0);
    FENCE(); BAR();
    phase_ld<3>(lA0, lB0, wm, wn, lane16, kl, af, bf2);
    stageB_g1(gB(ktE2), lB0, 1, t);
    FENCE(); BAR();
    __builtin_amdgcn_s_setprio(1); phase_mm<3>(af, bf2, acc); __builtin_amdgcn_s_setprio(0);
    VMW4();
    BAR();
    phase_ld<0>(lA1, lB1, wm, wn, lane16, kl, af, bf2);
    stageB_g1(gB(ktE2), lB0, 0, t);
    FENCE(); BAR();
    __builtin_amdgcn_s_setprio(1); phase_mm<0>(af, bf2, acc); __builtin_amdgcn_s_setprio(0);
    FENCE(); BAR();
    phase_ld<1>(lA1, lB1, wm, wn, lane16, kl, af, bf2);
    stageA_g1(gA(ktE2), lA0, 1, t);
    FENCE(); BAR();
    __builtin_amdgcn_s_setprio(1); phase_mm<1>(af, bf2, acc); __builtin_amdgcn_s_setprio(0);
    FENCE(); BAR();
    phase_ld<2>(lA1, lB1, wm, wn, lane16, kl, af, bf2);
    stageA_g1(gA(ktO2), lA1, 0, t);
    FENCE(); BAR();
    __builtin_amdgcn_s_setprio(1); phase_mm<2>(af, bf2, acc); __builtin_amdgcn_s_setprio(0);
    FENCE(); BAR();
    phase_ld<3>(lA1, lB1, wm, wn, lane16, kl, af, bf2);
    stageB_g1(gB(ktO2), lB1, 1, t);
    FENCE(); BAR();
    __builtin_amdgcn_s_setprio(1); phase_mm<3>(af, bf2, acc); __builtin_amdgcn_s_setprio(0);
    VMW4();
    BAR();
  }

  // ---- peeled last iteration (i == 3) with split epilogue ----
  float en[4];
#pragma unroll
  for (int nf = 0; nf < 4; ++nf) en[nf] = enorm[k0 + wn * 64 + nf * 16 + lane16];
  float* ldsS = (float*)&lds[0][0][0];   // [256][4] in dead buf0 A-region
  float* ldsT = ldsS + 1024;             // [256][4]
  {
    phase_ld<0>(lA0, lB0, wm, wn, lane16, kl, af, bf2);
    stageB_g1(gB(7), lB1, 0, t);
    FENCE(); BAR();
    __builtin_amdgcn_s_setprio(1); phase_mm<0>(af, bf2, acc); __builtin_amdgcn_s_setprio(0);
    FENCE(); BAR();
    phase_ld<1>(lA0, lB0, wm, wn, lane16, kl, af, bf2);
    stageA_g1(gA(7), lA1, 1, t);
    FENCE(); BAR();
    __builtin_amdgcn_s_setprio(1); phase_mm<1>(af, bf2, acc); __builtin_amdgcn_s_setprio(0);
    FENCE(); BAR();
    phase_ld<2>(lA0, lB0, wm, wn, lane16, kl, af, bf2);
    FENCE(); BAR();
    __builtin_amdgcn_s_setprio(1); phase_mm<2>(af, bf2, acc); __builtin_amdgcn_s_setprio(0);
    FENCE(); BAR();
    phase_ld<3>(lA0, lB0, wm, wn, lane16, kl, af, bf2);
    FENCE(); BAR();
    __builtin_amdgcn_s_setprio(1); phase_mm<3>(af, bf2, acc); __builtin_amdgcn_s_setprio(0);
    VMW0();
    BAR();
    phase_ld<0>(lA1, lB1, wm, wn, lane16, kl, af, bf2);
    FENCE(); BAR();
    __builtin_amdgcn_s_setprio(1); phase_mm<0>(af, bf2, acc); __builtin_amdgcn_s_setprio(0);
    FENCE(); BAR();
    phase_ld<1>(lA1, lB1, wm, wn, lane16, kl, af, bf2);
    FENCE(); BAR();
    __builtin_amdgcn_s_setprio(1); phase_mm<1>(af, bf2, acc); __builtin_amdgcn_s_setprio(0);
    // m-rows 0..127 complete -> first epilogue half drains under ph6/ph7
    EPI_HALF(0);
    FENCE(); BAR();
    phase_ld<2>(lA1, lB1, wm, wn, lane16, kl, af, bf2);
    FENCE(); BAR();
    __builtin_amdgcn_s_setprio(1); phase_mm<2>(af, bf2, acc); __builtin_amdgcn_s_setprio(0);
    FENCE(); BAR();
    phase_ld<3>(lA1, lB1, wm, wn, lane16, kl, af, bf2);
    FENCE(); BAR();
    __builtin_amdgcn_s_setprio(1); phase_mm<3>(af, bf2, acc); __builtin_amdgcn_s_setprio(0);
    EPI_HALF(4);
  }
  __syncthreads();
  {
    int rr = t & 255;
    if (t < 256) {
      float v = ldsS[rr * 4 + 0] + ldsS[rr * 4 + 1] + ldsS[rr * 4 + 2] + ldsS[rr * 4 + 3];
      S1p[ct * 16384 + n0 + rr] = v;
    } else {
      float v = ldsT[rr * 4 + 0] + ldsT[rr * 4 + 1] + ldsT[rr * 4 + 2] + ldsT[rr * 4 + 3];
      STp[ct * 16384 + n0 + rr] = v;
    }
  }
}

// ========== fused tail: per-block sequential {softmax tile -> gemm2 tile} =====
__device__ __forceinline__ void stageA2(const u16* __restrict__ g, u16* l, int h, int t) {
  int ri = t >> 3, ch = t & 7;
  int r = (ri >> 5) * 64 + h * 32 + (ri & 31);
  g2l16(g + (size_t)r * 4096 + ((ch ^ (r & 7)) * 8), l + r * 64 + ch * 8);
}
__device__ __forceinline__ void stageB2(const u16* __restrict__ g, u16* l, int h, int j, int t) {
  int ri = j * 64 + (t >> 3), ch = t & 7;
  int r = (ri >> 5) * 64 + h * 32 + (ri & 31);
  g2l16(g + (size_t)r * 4096 + ((ch ^ (r & 7)) * 8), l + r * 64 + ch * 8);
}

template<int P>
__device__ __forceinline__ void phase_ldN(const u16* Ab, const u16* Bb,
    int wm, int wn, int lane16, int kl, bf16x8 (&af)[2][2], bf16x8 (&bf)[4][2]) {
  int sw = lane16 & 7;
#pragma unroll
  for (int m = 0; m < 2; ++m)
#pragma unroll
    for (int s = 0; s < 2; ++s)
      af[m][s] = *(const bf16x8*)(Ab + (wm * 64 + (P * 2 + m) * 16 + lane16) * 64
                                  + (((s * 4 + kl) ^ sw) * 8));
  if constexpr (P == 0) {
#pragma unroll
    for (int n = 0; n < 4; ++n)
#pragma unroll
      for (int s = 0; s < 2; ++s)
        bf[n][s] = *(const bf16x8*)(Bb + (wn * 64 + n * 16 + lane16) * 64
                                    + (((s * 4 + kl) ^ sw) * 8));
  }
}
template<int P>
__device__ __forceinline__ void phase_mmN(bf16x8 (&af)[2][2], bf16x8 (&bf)[4][2],
                                          f32x4 (&acc)[4][4]) {
#pragma unroll
  for (int m = 0; m < 2; ++m)
#pragma unroll
    for (int n = 0; n < 4; ++n)
#pragma unroll
      for (int s = 0; s < 2; ++s)
        acc[P * 2 + m][n] = __builtin_amdgcn_mfma_f32_16x16x32_bf16(
            af[m][s], bf[n][s], acc[P * 2 + m][n], 0, 0, 0);
}

#define G2_TILE(Ab, Bb, An, Bn, kn, ST, LASTW) \
  { const u16* gAn = gA + (kn) * 64; const u16* gBn = gB + (kn) * 64; \
    phase_ldN<0>(Ab, Bb, wm, wn, lane16, kl, af, bf); \
    if (ST) { stageA2(gAn, An, 0, t); stageA2(gAn, An, 1, t); } \
    FENCE(); BAR(); \
    __builtin_amdgcn_s_setprio(1); phase_mmN<0>(af, bf, acc); __builtin_amdgcn_s_setprio(0); \
    FENCE(); BAR(); \
    phase_ldN<1>(Ab, Bb, wm, wn, lane16, kl, af, bf); \
    if (ST) { stageB2(gBn, Bn, 0, 0, t); stageB2(gBn, Bn, 0, 1, t); \
              stageB2(gBn, Bn, 1, 0, t); stageB2(gBn, Bn, 1, 1, t); } \
    FENCE(); BAR(); \
    __builtin_amdgcn_s_setprio(1); phase_mmN<1>(af, bf, acc); __builtin_amdgcn_s_setprio(0); \
    if (!(LASTW)) { if (ST) { VMW6(); } else { VMW0(); } BAR(); } }

__global__ __launch_bounds__(512, 1) void fused_tail(const float* __restrict__ D,
    const float* __restrict__ xnorm, const float* __restrict__ STp,
    float* __restrict__ assign, const u16* __restrict__ Et,
    const u16* __restrict__ Pu, const float* __restrict__ S1p, float* __restrict__ Q) {
  __shared__ __align__(16) u16 lds3[3][384 * 64];  // 144 KB
  int bid = blockIdx.x;
  int t = threadIdx.x;

  int s2 = (bid & 7) * 32 + (bid >> 3);
  int ct = s2 >> 2, rt2 = s2 & 3;
  int c0 = rt2 << 7, n0g = ct << 8;
  const u16* gA = Et + (size_t)c0 * 4096;
  const u16* gB = Pu + (size_t)n0g * 4096;
  u16* A0 = &lds3[0][0]; u16* B0 = &lds3[0][128 * 64];
  u16* A1 = &lds3[1][0]; u16* B1 = &lds3[1][128 * 64];
  u16* A2 = &lds3[2][0]; u16* B2 = &lds3[2][128 * 64];

  // pre-stage gemm2 tile 0 into buf0 (latency hides under softmax phase)
  stageA2(gA + 0 * 64, A0, 0, t); stageA2(gA + 0 * 64, A0, 1, t);
  stageB2(gB + 0 * 64, B0, 0, 0, t); stageB2(gB + 0 * 64, B0, 0, 1, t);
  stageB2(gB + 0 * 64, B0, 1, 0, t); stageB2(gB + 0 * 64, B0, 1, 1, t);

  // ---------------- phase 1: softmax tile (tt overlays buf1/buf2) -------------
  {
    float (*tt)[132] = (float(*)[132])&lds3[1][0];
    int ng = bid >> 1, kh = bid & 1;
    int n0 = ng << 7;
    int b = n0 >> 10, hw0 = n0 & 1023;
    int i = t >> 2, jc = t & 3;
    int row = n0 + i;
    float sT = 0.f;
#pragma unroll
    for (int p = 0; p < 4; ++p) sT += STp[(jc * 4 + p) * 16384 + row];
    sT += __shfl_xor(sT, 1); sT += __shfl_xor(sT, 2);
    float isT = 1.0f / sT;
    float xn = xnorm[row];
    int kbase = kh << 11;
    const float* Dr = D + (size_t)row * 4096 + kbase;
    float* assignB = assign + (size_t)b * 4194304 + hw0;

    for (int kt = 0; kt < 16; ++kt) {
      int kb = kt << 7;
#pragma unroll
      for (int it = 0; it < 8; ++it) {
        int col4 = it * 16 + jc * 4;
        float4 dv = *(const float4*)(Dr + kb + col4);
        tt[col4 + 0][i] = __expf((xn - dv.x) * INVT - CSH) * isT;
        tt[col4 + 1][i] = __expf((xn - dv.y) * INVT - CSH) * isT;
        tt[col4 + 2][i] = __expf((xn - dv.z) * INVT - CSH) * isT;
        tt[col4 + 3][i] = __expf((xn - dv.w) * INVT - CSH) * isT;
      }
      __syncthreads();
#pragma unroll
      for (int p = 0; p < 8; ++p) {
        int idx = t + (p << 9);
        int j = idx >> 5, ic = idx & 31;
        f32x4 o;
        o[0] = tt[j][ic * 4 + 0]; o[1] = tt[j][ic * 4 + 1];
        o[2] = tt[j][ic * 4 + 2]; o[3] = tt[j][ic * 4 + 3];
        __builtin_nontemporal_store(o,
            (f32x4*)(assignB + (size_t)(kbase + kb + j) * 1024 + ic * 4));
      }
      __syncthreads();
    }
  }

  // ---------------- phase 2: gemm2 tile (3-deep, 2-phase/tile) ----------------
  int l = t & 63, w = t >> 6;
  int wm = w >> 2, wn = w & 3;
  int lane16 = l & 15, kl = l >> 4;

  f32x4 acc[4][4];
#pragma unroll
  for (int m = 0; m < 4; ++m)
#pragma unroll
    for (int n = 0; n < 4; ++n) acc[m][n] = f32x4{0.f, 0.f, 0.f, 0.f};
  bf16x8 af[2][2], bf[4][2];

  stageA2(gA + 1 * 64, A1, 0, t); stageA2(gA + 1 * 64, A1, 1, t);
  stageB2(gB + 1 * 64, B1, 0, 0, t); stageB2(gB + 1 * 64, B1, 0, 1, t);
  stageB2(gB + 1 * 64, B1, 1, 0, t); stageB2(gB + 1 * 64, B1, 1, 1, t);
  VMW6();
  BAR();

#pragma unroll 1
  for (int j = 0; j < 20; ++j) {
    int kt = 3 * j;
    G2_TILE(A0, B0, A2, B2, kt + 2, 1, 0);
    G2_TILE(A1, B1, A0, B0, kt + 3, 1, 0);
    G2_TILE(A2, B2, A1, B1, kt + 4, 1, 0);
  }
  G2_TILE(A0, B0, A2, B2, 62, 1, 0);
  G2_TILE(A1, B1, A0, B0, 63, 1, 0);
  G2_TILE(A2, B2, A1, B1, 0, 0, 0);
  G2_TILE(A0, B0, A1, B1, 0, 0, 1);

  float iv[4];
#pragma unroll
  for (int nn = 0; nn < 4; ++nn) {
    int col = n0g + wn * 64 + nn * 16 + lane16;
    float ssum = 0.f;
#pragma unroll
    for (int j = 0; j < 16; ++j) ssum += S1p[j * 16384 + col];
    iv[nn] = 1.0f / ssum;
  }
  for (int m = 0; m < 4; ++m) {
    for (int r = 0; r < 4; ++r) {
      int crow = c0 + wm * 64 + m * 16 + kl * 4 + r;
      for (int nn = 0; nn < 4; ++nn) {
        int col = n0g + wn * 64 + nn * 16 + lane16;
        int bb = col >> 10, hw = col & 1023;
        __builtin_nontemporal_store(acc[m][nn][r] * iv[nn],
                                    &Q[bb * 524288 + crow * 1024 + hw]);
      }
    }
  }
}

extern "C" void kernel_launch(void* const* d_in, const int* in_sizes, int n_in,
                              void* d_out, int out_size, void* d_ws, size_t ws_size,
                              hipStream_t stream) {
  const float* feat = (const float*)d_in[0];   // (16, 512, 32, 32)
  const float* cb = (const float*)d_in[1];     // (4096, 512)
  float* out = (float*)d_out;
  float* q_out = out;                          // 8388608
  float* a_out = out + 8388608;                // 67108864
  float* d_dist = out + 75497472;              // 67108864

  char* ws = (char*)d_ws;
  u16* Xh = (u16*)(ws + 0);                    // 16 MB  fp16 X (n,c)
  u16* Eh = (u16*)(ws + 16777216);             // 4 MB   fp16 E (k,c)
  u16* Et = (u16*)(ws + 20971520);             // 4 MB   bf16 E^T (c,k) pi-order
  float* xnorm = (float*)(ws + 25165824);      // 64 KB
  float* enorm = (float*)(ws + 25231360);      // 16 KB
  float* S1p = (float*)(ws + 25247744);        // 1 MB  [16][16384]
  float* STp = (float*)(ws + 26296320);        // 1 MB
  u16* Pu = (u16*)(ws + 27410432);             // 128 MB -> ends ~155 MB

  prep_all<<<320, 256, 0, stream>>>(feat, cb, Xh, xnorm, Eh, enorm, Et);
  gemm1_8ph<<<1024, 512, 0, stream>>>(Xh, Eh, xnorm, enorm, d_dist, S1p, STp, Pu);
  fused_tail<<<256, 512, 0, stream>>>(d_dist, xnorm, STp, a_out, Et, Pu, S1p, q_out);
}